// Round 7
// baseline (1005.572 us; speedup 1.0000x reference)
//
#include <hip/hip_runtime.h>
#include <cstddef>

#define Nn 32
#define Cc 128
#define Tt 128
#define Vv 25
#define BN_INV 0.9999950000374997f

// ---------------- workspace layout (float offsets), max 53,192,000 ----------
// WB (bf16 weights)    @ 0          (159,744 f)
// QKBF  [n][192][3200] @ 200,000    row-major (att_s reads it)
// S1BF_T [n][3200][128]@ 200,000    (reuse, qk dead)  k-contig transposed
// ATSB  [n][3][t][625] @ 10,030,400
// Y2BF_T [n][3200][384]@ 13,870,400 k-contig transposed (dead after s1 GEMM)
// TOUTB_T padded       @ 23,710,000 (13,721,600 sh: 32n x [9600|409600|9600])
// SOUT  fp32           @ 33,531,200 row-major, live til TCN
// ATTB  [n][u][512]    @ 200,000    (reuse; dead after t1)
// XBARB_T [n][t][c]    @ 1,300,000  k-contig transposed
// QKT   fp32           @ 1,600,000  row-major
// TMPB_T [n][(m*25+v)][t] @ 2,700,000 (spans f 2.7M..28.91M!) dead after t1
// T1BF_T [n][3200][128]@ 46,638,400 k-contig transposed
// TOUT  fp32           @ 2,700,000  row-major (reuse, TMPB dead; ends 15.81M)
// !! OVERLAP CHAIN (R5/R6 bug): TOUTBP lies inside BOTH Y2's range AND
// TMPB's range. Margin zeroing (k_zpad) must run AFTER the t1 GEMM (last
// TMPB reader); TMPB's writes were clobbering earlier-zeroed margins.
// R4 LESSON: XCD swizzle cut TCN FETCH 126->39.5MB but dur unchanged ->
// GEMMs are issue/latency-bound, not BW-bound. R5-R7: global_load_lds staging
// (4 VMEM/phase vs 18) + k-contiguous B layouts. Keep 2-barrier structure
// (R3: explicit dbuf pipeline regressed) and XCD swizzle.

typedef __attribute__((ext_vector_type(8))) short bf16x8;
typedef __attribute__((ext_vector_type(4))) short short4v;
typedef __attribute__((ext_vector_type(4))) float f32x4;

__device__ __forceinline__ unsigned short f2bf(float f) {
    union { float f; unsigned u; } x; x.f = f;
    return (unsigned short)((x.u + 0x7FFFu + ((x.u >> 16) & 1u)) >> 16);
}
__device__ __forceinline__ float bf2f(unsigned short s) {
    union { unsigned u; float f; } x; x.u = ((unsigned)s) << 16;
    return x.f;
}

// async global->LDS 16B: lds dest = wave-uniform base + lane*16
__device__ __forceinline__ void gload16(const unsigned short* g, short* l) {
    __builtin_amdgcn_global_load_lds(
        (const __attribute__((address_space(1))) void*)g,
        (__attribute__((address_space(3))) void*)l, 16, 0, 0);
}

// =====================================================================
// MFMA bf16 GEMM, tile 128x128, 256 thr = 4 waves, K-block 32.
// Staging via global_load_lds (4x dwordx4 per thread-phase; wave w's instr q
// covers m/col-frag 2w+q; lane l -> slot frag*64 + (l&15) + 16*(l>>4) ==
// the MFMA fragment layout, so frag reads are unchanged).
// XCD swizzle: w = (b&7)*(nwg>>3) + (b>>3); n = w/gxn (whole n per XCD).
// BMODE 0: bf16 k-contiguous [col][ldb=K-stride]   (gload)
// BMODE 1: TCN: B[k=(kidx,c)][e] = BnPad[e*128+c], e=col+(kidx-3)*25,
//          per-n zero margins of 9600 elems make OOB taps read 0   (gload)
// BMODE 3: tein: B[k=(h,t)][col] = Bn[cb*128 + h*409600 + t]       (gload)
// BMODE 4: fp32 row-major [K][ldb], f2bf in regs, ds_write          (reg)
// DMODE 0: D/Dbf row-major m*ldd+col
// DMODE 1: Dbf transposed [col][128] packed short4 (M==128); D/resp row-major
// DMODE 2: t1: m=u, col=(c,v); Dbf=T1T[(u*25+v)*128+c]; resp=c*3200+u*25+v
// DMODE 3: tmp: col=(t,v); Dbf=TMPT[(m*25+v)*128+t]
// OM: 0 fp32 D only, 1 bf16 Dbf only, 2 both
// =====================================================================
template<int BMODE, int DMODE, int OM>
__global__ __launch_bounds__(256, 4) void gemm_k(
    const unsigned short* __restrict__ A, const void* __restrict__ Bv,
    float* __restrict__ D, unsigned short* __restrict__ Dbf,
    const float* __restrict__ resp, const float* __restrict__ bias,
    const float* __restrict__ gg, const float* __restrict__ bb,
    int M, int K, int lda, int ldb, int ldd,
    long an_stride, long bn_stride, long dn_stride, long dbfn,
    int gn, int gxn)
{
    __shared__ __attribute__((aligned(16))) short Al[8*64*8];  // 8KB
    __shared__ __attribute__((aligned(16))) short Bl[8*64*8];  // 8KB

    const int nwg = gridDim.x;
    const int b   = blockIdx.x;
    const int w   = (b & 7)*(nwg >> 3) + (b >> 3);
    const int n   = w / gxn;
    const int rem = w - n*gxn;
    const int mt  = rem / gn;
    const int nt  = rem - mt*gn;
    const int m0 = mt*128;
    const int j0 = nt*128;

    const unsigned short* An = A + (size_t)n*an_stride;

    const int tid = threadIdx.x;
    const int wav = tid >> 6, lane = tid & 63;
    const int lq = lane >> 4, l16 = lane & 15;

    // ---- gload address setup ----
    const int la = lane & 15;
    const int ka = (lane >> 4) << 3;            // k-octet elem offset
    const unsigned short* gA0 = An + (size_t)(m0 + (2*wav+0)*16 + la)*lda + ka;
    const unsigned short* gA1 = An + (size_t)(m0 + (2*wav+1)*16 + la)*lda + ka;
    short* lA0 = Al + (size_t)((2*wav+0)*64)*8;
    short* lA1 = Al + (size_t)((2*wav+1)*64)*8;
    short* lB0 = Bl + (size_t)((2*wav+0)*64)*8;
    short* lB1 = Bl + (size_t)((2*wav+1)*64)*8;
    const unsigned short* BnU = (const unsigned short*)Bv + (size_t)n*bn_stride;
    const int cb0 = j0 + (2*wav+0)*16 + la;
    const int cb1 = j0 + (2*wav+1)*16 + la;
    const unsigned short* gB0 = nullptr;
    const unsigned short* gB1 = nullptr;
    if (BMODE == 0) {
        gB0 = BnU + (size_t)cb0*ldb + ka;
        gB1 = BnU + (size_t)cb1*ldb + ka;
    } else if (BMODE == 1 || BMODE == 3) {
        gB0 = BnU + (size_t)cb0*128 + ka;   // (o*25+v)==cb for BMODE 3
        gB1 = BnU + (size_t)cb1*128 + ka;
    }
    // mode-4 reg staging ids
    const int scol = tid & 127, skq = tid >> 7;
    const int bcol = j0 + scol;

    f32x4 acc[2][8];
    #pragma unroll
    for (int i = 0; i < 2; ++i)
        #pragma unroll
        for (int c = 0; c < 8; ++c) acc[i][c] = (f32x4){0.f,0.f,0.f,0.f};

    for (int k0 = 0; k0 < K; k0 += 32) {
        bf16x8 b0r, b1r;
        if (BMODE == 4) {   // fp32 row-major -> bf16 regs (issue before barrier)
            const float* Bf = (const float*)Bv + (size_t)n*bn_stride;
            #pragma unroll
            for (int j = 0; j < 8; ++j)
                b0r[j] = (short)f2bf(Bf[(size_t)(k0 + skq*16 + j)*ldb + bcol]);
            #pragma unroll
            for (int j = 0; j < 8; ++j)
                b1r[j] = (short)f2bf(Bf[(size_t)(k0 + skq*16 + 8 + j)*ldb + bcol]);
        }

        __syncthreads();   // previous tile fully consumed
        gload16(gA0 + k0, lA0);
        gload16(gA1 + k0, lA1);
        if (BMODE == 0) {
            gload16(gB0 + k0, lB0);
            gload16(gB1 + k0, lB1);
        } else if (BMODE == 1) {
            const int off = ((k0 >> 7) - 3)*3200 + (k0 & 127);
            gload16(gB0 + off, lB0);
            gload16(gB1 + off, lB1);
        } else if (BMODE == 3) {
            const int off = (k0 >> 7)*409600 + (k0 & 127);
            gload16(gB0 + off, lB0);
            gload16(gB1 + off, lB1);
        } else {
            short* Bp = Bl + ((size_t)((scol>>4)*64 + (scol&15) + 32*skq))*8;
            *(bf16x8*)Bp = b0r;
            *(bf16x8*)(Bp + 128) = b1r;
        }
        __syncthreads();   // implicit vmcnt(0) drains gloads -> tile ready

        bf16x8 afr[2], bfr[8];
        afr[0] = *(const bf16x8*)(Al + ((size_t)((2*wav+0)*64 + lane))*8);
        afr[1] = *(const bf16x8*)(Al + ((size_t)((2*wav+1)*64 + lane))*8);
        #pragma unroll
        for (int c = 0; c < 8; ++c)
            bfr[c] = *(const bf16x8*)(Bl + ((size_t)(c*64 + lane))*8);
        #pragma unroll
        for (int i = 0; i < 2; ++i)
            #pragma unroll
            for (int c = 0; c < 8; ++c)
                acc[i][c] = __builtin_amdgcn_mfma_f32_16x16x32_bf16(
                    afr[i], bfr[c], acc[i][c], 0, 0, 0);
    }

    // ---- epilogue: row = m0+(2w+i)*16+lq*4+r ; col = j0+ct*16+l16 ----
    #pragma unroll
    for (int i = 0; i < 2; ++i) {
        const int mbase = m0 + (2*wav + i)*16 + lq*4;
        #pragma unroll
        for (int ct = 0; ct < 8; ++ct) {
            const int col = j0 + ct*16 + l16;
            if (DMODE == 0) {
                #pragma unroll
                for (int r = 0; r < 4; ++r) {
                    const int mg = mbase + r;
                    if (mg < M) {
                        const size_t addr = (size_t)mg*ldd + col + (size_t)n*dn_stride;
                        float val = acc[i][ct][r] + (bias ? bias[mg] : 0.f);
                        if (gg) {
                            val = val*(gg[mg]*BN_INV) + bb[mg] + resp[addr];
                            val = val > 0.f ? val : 0.1f*val;
                        }
                        if (OM != 1) D[addr] = val;
                        if (OM >= 1) Dbf[addr] = f2bf(val);
                    }
                }
            } else if (DMODE == 1) {   // Dbf transposed [col][128] (M==128)
                short4v pk;
                #pragma unroll
                for (int r = 0; r < 4; ++r) {
                    const int mg = mbase + r;
                    const size_t addr = (size_t)mg*ldd + col + (size_t)n*dn_stride;
                    float val = acc[i][ct][r] + (bias ? bias[mg] : 0.f);
                    if (gg) {
                        val = val*(gg[mg]*BN_INV) + bb[mg] + resp[addr];
                        val = val > 0.f ? val : 0.1f*val;
                    }
                    if (OM != 1) D[addr] = val;
                    pk[r] = (short)f2bf(val);
                }
                *(short4v*)(Dbf + (size_t)col*128 + mbase + (size_t)n*dbfn) = pk;
            } else if (DMODE == 2) {   // t1: m=u, col=(c,v)
                const int c = col/25, v = col - 25*c;
                const float bi = bias ? bias[c] : 0.f;
                float gv = 0.f, b2 = 0.f;
                if (gg) { gv = gg[c]*BN_INV; b2 = bb[c]; }
                #pragma unroll
                for (int r = 0; r < 4; ++r) {
                    const int u = mbase + r;
                    float val = acc[i][ct][r] + bi;
                    if (gg) {
                        val = val*gv + b2 + resp[(size_t)c*3200 + (size_t)u*25 + v
                                                 + (size_t)n*dn_stride];
                        val = val > 0.f ? val : 0.1f*val;
                    }
                    Dbf[(size_t)(u*25 + v)*128 + c + (size_t)n*dbfn] = f2bf(val);
                }
            } else {                   // DMODE 3: tmp: col=(t,v)
                const int t = col/25, v = col - 25*t;
                #pragma unroll
                for (int r = 0; r < 4; ++r) {
                    const int mg = mbase + r;
                    float val = acc[i][ct][r] + (bias ? bias[mg] : 0.f);
                    Dbf[((size_t)mg*25 + v)*128 + t + (size_t)n*dbfn] = f2bf(val);
                }
            }
        }
    }
}

// weight prep: convert (and permute) all weights to bf16 in WB
__global__ void k_prep(const float* __restrict__ wis, const float* __restrict__ wos,
                       const float* __restrict__ wfs, const float* __restrict__ wit,
                       const float* __restrict__ wot, const float* __restrict__ wft,
                       const float* __restrict__ wtc, unsigned short* __restrict__ W) {
    int i = blockIdx.x*256 + threadIdx.x;
    if (i < 24576) { W[i] = f2bf(wis[i]); return; }          i -= 24576;
    if (i < 49152) { W[24576 + i] = f2bf(wos[i]); return; }  i -= 49152;
    if (i < 16384) { W[73728 + i] = f2bf(wfs[i]); return; }  i -= 16384;
    if (i < 32768) { W[90112 + i] = f2bf(wit[i]); return; }  i -= 32768;
    if (i < 65536) { // [(h*128+o)][c] <- wot[o][h*128+c]
        int ho = i >> 7, c = i & 127; int h = ho >> 7, o = ho & 127;
        W[122880 + i] = f2bf(wot[o*512 + h*128 + c]); return; } i -= 65536;
    if (i < 16384) { W[188416 + i] = f2bf(wft[i]); return; } i -= 16384;
    if (i < 114688) { // [o][kidx*128+c] <- wtc[(o*128+c)*7 + kidx]
        int o = i / 896; int r = i - o*896; int kidx = r >> 7, c = r & 127;
        W[204800 + i] = f2bf(wtc[(o*128 + c)*7 + kidx]); }
}

// zero the TCN pad margins: per n, shorts [0,9600) and [419200,428800)
// of the 428800-stride block. MUST run after the t1 GEMM: TOUTBP overlaps
// BOTH Y2BF (k_eins) and TMPB (tmp GEMM) — t1 is the last TMPB reader.
// (R5 bug: zeroed at launch top, clobbered by k_eins AND tmp;
//  R6 bug: zeroed after s1, still clobbered by tmp.)
__global__ void k_zpad(unsigned short* __restrict__ p) {
    int i = blockIdx.x*256 + threadIdx.x;     // 76800 threads x 8 shorts
    if (i >= 76800) return;
    int chunk = i*8;
    int n = chunk / 19200;
    int r = chunk - n*19200;
    size_t addr = (size_t)n*428800 + (size_t)(r < 9600 ? r : 419200 + (r - 9600));
    *(bf16x8*)(p + addr) = (bf16x8){0,0,0,0,0,0,0,0};
}

// spatial attention: atts_bf = att0 + tanh(q.k/32)*alpha  (reads bf16 qk)
__global__ void k_att_s(const unsigned short* __restrict__ qk,
                        const float* __restrict__ att0,
                        const float* __restrict__ alphas,
                        unsigned short* __restrict__ att) {
    int b = blockIdx.x;
    int n = b / (3*Tt); int rem = b - n*(3*Tt); int s = rem / Tt; int t = rem - s*Tt;
    __shared__ float qs[32*Vv], ks[32*Vv];
    const unsigned short* qp = qk + (size_t)n*614400 + (size_t)(s*32)*3200 + t*25;
    const unsigned short* kp = qk + (size_t)n*614400 + (size_t)(96 + s*32)*3200 + t*25;
    for (int i = threadIdx.x; i < 32*Vv; i += 256) {
        int c = i / Vv, v = i - c*Vv;
        qs[i] = bf2f(qp[(size_t)c*3200 + v]);
        ks[i] = bf2f(kp[(size_t)c*3200 + v]);
    }
    __syncthreads();
    float alpha = alphas[s];
    for (int i = threadIdx.x; i < Vv*Vv; i += 256) {
        int u = i / Vv, v = i - u*Vv;
        float a = 0.f;
        #pragma unroll
        for (int c = 0; c < 32; ++c) a += qs[c*Vv + u] * ks[c*Vv + v];
        att[(size_t)n*240000 + (size_t)s*80000 + (size_t)t*625 + i] =
            f2bf(att0[s*625 + i] + tanhf(a * (1.f/32.f)) * alpha);
    }
}

// =====================================================================
// MFMA spatial einsum -> Y2 TRANSPOSED: y2T[col=t*25+v][s*128+c]
// One block per (n, 4 consecutive t); block-diagonal B over the 4 t's.
// =====================================================================
__global__ __launch_bounds__(256, 2) void k_eins_mfma(
    const float* __restrict__ X, const unsigned short* __restrict__ att,
    unsigned short* __restrict__ y2)
{
    __shared__ short Xf[128*128];     // [c][tl*32+u] bf16, swizzled (32KB)
    __shared__ short Bf[7*4*64*8];    // frag [nt][ks][lane][j] (28KB)

    const int n  = blockIdx.x >> 5;
    const int t0 = (blockIdx.x & 31) * 4;
    const int tid = threadIdx.x;
    const int wav = tid >> 6, lane = tid & 63;
    const int lq = lane >> 4, l16 = lane & 15;

    for (int i = tid; i < 7*4*64; i += 256)
        *(bf16x8*)(Bf + (size_t)i*8) = (bf16x8){0,0,0,0,0,0,0,0};

    const float* xp = X + (size_t)n*409600;
    for (int i = tid; i < 8192; i += 256) {
        int u2 = (i & 15)*2, tl = (i >> 4) & 3, c = i >> 6;
        float f0 = 0.f, f1 = 0.f;
        if (u2 < 25) {
            const float* p = xp + (size_t)c*3200 + (t0 + tl)*25 + u2;
            f0 = p[0];
            if (u2 < 24) f1 = p[1];
        }
        unsigned pk = (unsigned)f2bf(f0) | ((unsigned)f2bf(f1) << 16);
        int byte = (i*4) ^ ((c & 7) << 4);
        *(unsigned*)((char*)Xf + byte) = pk;
    }
    __syncthreads();

    bf16x8 afr[2][4];
    #pragma unroll
    for (int i = 0; i < 2; ++i) {
        const int c = (2*wav + i)*16 + l16;
        #pragma unroll
        for (int ks = 0; ks < 4; ++ks) {
            int byte = ((c*128 + ks*32 + lq*8)*2) ^ ((c & 7) << 4);
            afr[i][ks] = *(const bf16x8*)((const char*)Xf + byte);
        }
    }

    for (int s = 0; s < 3; ++s) {
        const unsigned short* ap = att + (size_t)n*240000 + (size_t)s*80000
                                       + (size_t)t0*625;
        for (int j = tid; j < 2500; j += 256) {
            int tl = j / 625, r = j - tl*625;
            int u = r / 25, v = r - u*25;
            int col = tl*25 + v;
            int l = ((u >> 3) << 4) | (col & 15);
            int nt = col >> 4;
            Bf[(size_t)((nt*4 + tl)*64 + l)*8 + (u & 7)] = (short)ap[j];
        }
        __syncthreads();

        f32x4 acc[2][7];
        #pragma unroll
        for (int i = 0; i < 2; ++i)
            #pragma unroll
            for (int nt = 0; nt < 7; ++nt) acc[i][nt] = (f32x4){0.f,0.f,0.f,0.f};

        #pragma unroll
        for (int ks = 0; ks < 4; ++ks) {
            bf16x8 bfr[7];
            #pragma unroll
            for (int nt = 0; nt < 7; ++nt)
                bfr[nt] = *(const bf16x8*)(Bf + (size_t)((nt*4 + ks)*64 + lane)*8);
            #pragma unroll
            for (int i = 0; i < 2; ++i)
                #pragma unroll
                for (int nt = 0; nt < 7; ++nt)
                    acc[i][nt] = __builtin_amdgcn_mfma_f32_16x16x32_bf16(
                        afr[i][ks], bfr[nt], acc[i][nt], 0, 0, 0);
        }

        // transposed write: y2T[(t0*25+col)*384 + s*128 + row..row+3]
        unsigned short* yb = y2 + (size_t)n*1228800;
        #pragma unroll
        for (int i = 0; i < 2; ++i) {
            const int row = (2*wav + i)*16 + lq*4;
            #pragma unroll
            for (int nt = 0; nt < 7; ++nt) {
                const int col = nt*16 + l16;
                if (col < 100) {
                    short4v pk;
                    #pragma unroll
                    for (int r = 0; r < 4; ++r) pk[r] = (short)f2bf(acc[i][nt][r]);
                    *(short4v*)(yb + (size_t)(t0*25 + col)*384 + s*128 + row) = pk;
                }
            }
        }
        __syncthreads();
    }
}

// xbarT[n][t*128 + c] = mean_v sout  (k-contiguous for qkt GEMM)
__global__ void k_mean(const float* __restrict__ X, unsigned short* __restrict__ xb) {
    int idx = blockIdx.x*256 + threadIdx.x;
    if (idx >= Nn*Cc*Tt) return;
    const float* p = X + (size_t)idx*25;
    float s = 0.f;
    #pragma unroll
    for (int v = 0; v < Vv; ++v) s += p[v];
    int n = idx >> 14, rem = idx & 16383, c = rem >> 7, t = rem & 127;
    xb[(size_t)n*16384 + (size_t)t*128 + c] = f2bf(s * (1.f/25.f));
}

// temporal attention: attb_bf[n][u][(h*128+t)] = mask*alpha*tanh(dot/32)
__global__ void k_att_t(const float* __restrict__ qkt, const float* __restrict__ af,
                        const float* __restrict__ ab, unsigned short* __restrict__ attb) {
    int n = blockIdx.x >> 2, h = blockIdx.x & 3;
    __shared__ float qs[32*Tt], ks[32*Tt];
    const float* qp = qkt + (size_t)n*32768 + (size_t)(h*32)*128;
    const float* kp = qkt + (size_t)n*32768 + (size_t)(128 + h*32)*128;
    for (int i = threadIdx.x; i < 32*Tt; i += 256) { qs[i] = qp[i]; ks[i] = kp[i]; }
    __syncthreads();
    float alpha = (h < 2) ? af[h] : ab[h-2];
    for (int i = threadIdx.x; i < Tt*Tt; i += 256) {
        int u = i >> 7, t = i & 127;
        bool keep = (h < 2) ? (t >= u) : (t <= u);
        float val = 0.f;
        if (keep) {
            float a = 0.f;
            #pragma unroll
            for (int c = 0; c < 32; ++c) a += qs[c*Tt + t] * ks[c*Tt + u];
            val = tanhf(a * (1.f/32.f)) * alpha;
        }
        attb[(size_t)n*65536 + (size_t)u*512 + h*128 + t] = f2bf(val);
    }
}

extern "C" void kernel_launch(void* const* d_in, const int* in_sizes, int n_in,
                              void* d_out, int out_size, void* d_ws, size_t ws_size,
                              hipStream_t stream) {
    const float* x       = (const float*)d_in[0];
    const float* w_in_s  = (const float*)d_in[1];
    const float* b_in_s  = (const float*)d_in[2];
    const float* att0s   = (const float*)d_in[3];
    const float* alphas  = (const float*)d_in[4];
    const float* w_out_s = (const float*)d_in[5];
    const float* b_out_s = (const float*)d_in[6];
    const float* g_out_s = (const float*)d_in[7];
    const float* be_out_s= (const float*)d_in[8];
    const float* w_ff_s  = (const float*)d_in[9];
    const float* b_ff_s  = (const float*)d_in[10];
    const float* g_ff_s  = (const float*)d_in[11];
    const float* be_ff_s = (const float*)d_in[12];
    const float* w_in_t  = (const float*)d_in[13];
    const float* b_in_t  = (const float*)d_in[14];
    const float* alphat_f= (const float*)d_in[15];
    const float* alphat_b= (const float*)d_in[16];
    const float* w_out_t = (const float*)d_in[17];
    const float* b_out_t = (const float*)d_in[18];
    const float* g_out_t = (const float*)d_in[19];
    const float* be_out_t= (const float*)d_in[20];
    const float* w_ff_t  = (const float*)d_in[21];
    const float* b_ff_t  = (const float*)d_in[22];
    const float* g_ff_t  = (const float*)d_in[23];
    const float* be_ff_t = (const float*)d_in[24];
    const float* w_tcn   = (const float*)d_in[25];
    const float* b_tcn   = (const float*)d_in[26];
    const float* g_tcn   = (const float*)d_in[27];
    const float* be_tcn  = (const float*)d_in[28];

    float* ws = (float*)d_ws;
    unsigned short* WB    = (unsigned short*)ws;
    unsigned short* QKBF  = (unsigned short*)(ws + 200000);
    unsigned short* S1BF  = (unsigned short*)(ws + 200000);   // transposed
    unsigned short* ATSB  = (unsigned short*)(ws + 10030400);
    unsigned short* Y2BF  = (unsigned short*)(ws + 13870400); // transposed
    unsigned short* TOUTBP= (unsigned short*)(ws + 23710000); // padded base
    unsigned short* TOUTB = TOUTBP + 9600;                    // e=0 of n=0
    float*          SOUT  = ws + 33531200;
    unsigned short* ATTB  = (unsigned short*)(ws + 200000);
    unsigned short* XBARB = (unsigned short*)(ws + 1300000);  // transposed
    float*          QKT   = ws + 1600000;
    unsigned short* TMPB  = (unsigned short*)(ws + 2700000);  // transposed
    unsigned short* T1BF  = (unsigned short*)(ws + 46638400); // transposed
    float*          TOUT  = ws + 2700000;
    float* out = (float*)d_out;

    unsigned short* wbis = WB;
    unsigned short* wbos = WB + 24576;
    unsigned short* wbfs = WB + 73728;
    unsigned short* wbit = WB + 90112;
    unsigned short* wbot = WB + 122880;
    unsigned short* wbft = WB + 188416;
    unsigned short* wbtc = WB + 204800;

    dim3 blk(256);
    const float* NUL = nullptr;

    k_prep<<<1248, blk, 0, stream>>>(w_in_s, w_out_s, w_ff_s, w_in_t,
                                     w_out_t, w_ff_t, w_tcn, WB);

    // ---- spatial ----
    // qk_bf = W_in_s @ x + b   (M=192, K=128, B=x fp32, D row-major)
    gemm_k<4,0,1><<<1600, blk, 0, stream>>>(
        wbis, x, nullptr, QKBF, NUL, b_in_s, NUL, NUL,
        192, 128, 128, 3200, 3200, 0L, 409600L, 614400L, 614400L, 25, 50);
    k_att_s<<<Nn*3*Tt, blk, 0, stream>>>(QKBF, att0s, alphas, ATSB);
    k_eins_mfma<<<dim3(Nn*32), blk, 0, stream>>>(x, ATSB, Y2BF);
    // s1T = lrelu(x + bn(W_out_s @ y2T + b))   (B=Y2T ldb=384)
    gemm_k<0,1,1><<<800, blk, 0, stream>>>(
        wbos, Y2BF, nullptr, S1BF, x, b_out_s, g_out_s, be_out_s,
        128, 384, 384, 384, 3200, 0L, 1228800L, 409600L, 409600L, 25, 25);
    // sout = lrelu(x + bn(W_ff_s @ s1T + b))   (D=SOUT fp32 row-major)
    gemm_k<0,0,0><<<800, blk, 0, stream>>>(
        wbfs, S1BF, SOUT, nullptr, x, b_ff_s, g_ff_s, be_ff_s,
        128, 128, 128, 128, 3200, 0L, 409600L, 409600L, 409600L, 25, 25);

    // ---- temporal ----
    k_mean<<<2048, blk, 0, stream>>>(SOUT, XBARB);
    // qkt = W_in_t @ xbarT + b   (M=256, B=XBARB_T ldb=128, D row-major)
    gemm_k<0,0,0><<<64, blk, 0, stream>>>(
        wbit, XBARB, QKT, nullptr, NUL, b_in_t, NUL, NUL,
        256, 128, 128, 128, 128, 0L, 16384L, 32768L, 32768L, 1, 2);
    k_att_t<<<Nn*4, blk, 0, stream>>>(QKT, alphat_f, alphat_b, ATTB);
    // tmpT[(m*25+v)][t] = W_out_t_perm @ sout  (M=512, B=SOUT fp32, DMODE3)
    gemm_k<4,3,1><<<3200, blk, 0, stream>>>(
        wbot, SOUT, nullptr, TMPB, NUL, NUL, NUL, NUL,
        512, 128, 128, 3200, 3200, 0L, 409600L, 1638400L, 1638400L, 25, 100);
    // t1T = lrelu(sout + bn(att @ tmpT + b))  (K=512, BMODE3, DMODE2)
    gemm_k<3,2,1><<<800, blk, 0, stream>>>(
        ATTB, TMPB, nullptr, T1BF, SOUT, b_out_t, g_out_t, be_out_t,
        128, 512, 512, 0, 3200, 65536L, 1638400L, 409600L, 409600L, 25, 25);
    // TMPB now dead -> safe to zero TCN pad margins (TOUTBP overlaps TMPB/Y2)
    k_zpad<<<300, blk, 0, stream>>>(TOUTBP);
    // tout fp32 + toutbT = lrelu(sout + bn(W_ff_t @ t1T + b))  (DMODE1 OM2)
    gemm_k<0,1,2><<<800, blk, 0, stream>>>(
        wbft, T1BF, TOUT, TOUTB, SOUT, b_ff_t, g_ff_t, be_ff_t,
        128, 128, 128, 128, 3200, 0L, 409600L, 409600L, 428800L, 25, 25);

    // ---- TCN ----
    // out = lrelu(tout + bn(conv7 @ toutbT + b))  (K=896, BMODE1 padded)
    gemm_k<1,0,0><<<800, blk, 0, stream>>>(
        wbtc, TOUTB, out, nullptr, TOUT, b_tcn, g_tcn, be_tcn,
        128, 896, 896, 0, 3200, 0L, 428800L, 409600L, 409600L, 25, 25);
}

// Round 9
// 892.020 us; speedup vs baseline: 1.1273x; 1.1273x over previous
//
#include <hip/hip_runtime.h>
#include <cstddef>

#define Nn 32
#define Cc 128
#define Tt 128
#define Vv 25
#define BN_INV 0.9999950000374997f

// ---------------- workspace layout (float offsets), max 53,192,000 ----------
// WB (bf16 weights)    @ 0          (159,744 f)
// QKBF  [n][192][3200] @ 200,000    row-major (att_s reads it)
// S1BF_T [n][3200][128]@ 200,000    (reuse, qk dead)  k-contig transposed
// ATSB  [n][3][t][625] @ 10,030,400
// Y2BF_T [n][3200][384]@ 13,870,400 k-contig transposed (dead after s1 GEMM)
// TOUTB_T padded       @ 23,710,000 (13,721,600 sh: 32n x [9600|409600|9600])
// SOUT  fp32           @ 33,531,200 row-major, live til TCN
// ATTB  [n][u][512]    @ 200,000    (reuse; dead after t1)
// XBARB_T [n][t][c]    @ 1,300,000  k-contig transposed
// QKT   fp32           @ 1,600,000  row-major
// TMPB_T [n][h][(v*128+o)][t] @ 2,700,000 (spans f 2.7M..28.91M!) dead after t1
// T1BF_T [n][3200][128]@ 46,638,400 k-contig transposed
// TOUT  fp32           @ 2,700,000  row-major (reuse, TMPB dead; ends 15.81M)
// !! OVERLAP CHAIN: TOUTBP lies inside BOTH Y2's AND TMPB's ranges. k_zpad
// must run AFTER the t1 GEMM (last TMPB reader). (R5/R6 bug.)
// R7 LESSON: transposed epilogues caused 9x write amplification (tmp GEMM
// WRITE_SIZE 941MB, 290us). R8: v-major cols for tmp/t1 + DMODE1 LDS flush.
// R8 BUG (NaN): flush decode used cl=idx>>3,m8=idx&7 -> read past Ot[64][136]
// and wrote cols j0+127 outside the tile. R9 fix: cl=idx>>4, m8=(idx&15)*8.
// Keep: gload staging (bank conflicts 0), XCD swizzle, 2-barrier loop.

typedef __attribute__((ext_vector_type(8))) short bf16x8;
typedef __attribute__((ext_vector_type(4))) short short4v;
typedef __attribute__((ext_vector_type(4))) float f32x4;

__device__ __forceinline__ unsigned short f2bf(float f) {
    union { float f; unsigned u; } x; x.f = f;
    return (unsigned short)((x.u + 0x7FFFu + ((x.u >> 16) & 1u)) >> 16);
}
__device__ __forceinline__ float bf2f(unsigned short s) {
    union { unsigned u; float f; } x; x.u = ((unsigned)s) << 16;
    return x.f;
}

// async global->LDS 16B: lds dest = wave-uniform base + lane*16
__device__ __forceinline__ void gload16(const unsigned short* g, short* l) {
    __builtin_amdgcn_global_load_lds(
        (const __attribute__((address_space(1))) void*)g,
        (__attribute__((address_space(3))) void*)l, 16, 0, 0);
}

// =====================================================================
// MFMA bf16 GEMM, tile 128x128, 256 thr = 4 waves, K-block 32.
// Staging via global_load_lds; XCD swizzle (whole n per XCD).
// BMODE 0: bf16 k-contiguous [col][ldb]                      (gload)
// BMODE 1: TCN: B[k=(kidx,c)][e] = BnPad[e*128+c], zero margins (gload)
// BMODE 3: t1:  B[k=(h,t)][col] = Bn[col*128 + h*409600 + t] (gload)
// BMODE 4: fp32 row-major [K][ldb], plain cols, f2bf in regs  (reg)
// BMODE 5: fp32 SOUT, V-MAJOR cols: col=(v,t), e=t*25+v       (reg)
// DMODE 0: D/Dbf row-major m*ldd+col
// DMODE 1: Dbf transposed [col][128] via LDS-transposed flush (M==128)
// DMODE 2: t1, V-MAJOR: v=j0>>7, c=lane-col; Dbf=T1T[(u*25+v)*128+c]
//          resp=c*3200+u*25+v; bias/g/b indexed by c. 32B write runs.
// DMODE 3: tmp, V-MAJOR: v=j0>>7, t=lane-col;
//          Dbf=TMP[(mg>>7)*409600+(v*128+(mg&127))*128+t]. 32B write runs.
// OM: 0 fp32 D only, 1 bf16 Dbf only, 2 both
// =====================================================================
template<int BMODE, int DMODE, int OM>
__global__ __launch_bounds__(256, 4) void gemm_k(
    const unsigned short* __restrict__ A, const void* __restrict__ Bv,
    float* __restrict__ D, unsigned short* __restrict__ Dbf,
    const float* __restrict__ resp, const float* __restrict__ bias,
    const float* __restrict__ gg, const float* __restrict__ bb,
    int M, int K, int lda, int ldb, int ldd,
    long an_stride, long bn_stride, long dn_stride, long dbfn,
    int gn, int gxn)
{
    __shared__ __attribute__((aligned(16))) short Al[8*64*8];  // 8KB
    __shared__ __attribute__((aligned(16))) short Bl[8*64*8];  // 8KB
    __shared__ __attribute__((aligned(16))) short Ot[(DMODE==1) ? 64*136 : 4];

    const int nwg = gridDim.x;
    const int b   = blockIdx.x;
    const int w   = (b & 7)*(nwg >> 3) + (b >> 3);
    const int n   = w / gxn;
    const int rem = w - n*gxn;
    const int mt  = rem / gn;
    const int nt  = rem - mt*gn;
    const int m0 = mt*128;
    const int j0 = nt*128;

    const unsigned short* An = A + (size_t)n*an_stride;

    const int tid = threadIdx.x;
    const int wav = tid >> 6, lane = tid & 63;
    const int lq = lane >> 4, l16 = lane & 15;

    // ---- gload address setup ----
    const int la = lane & 15;
    const int ka = (lane >> 4) << 3;            // k-octet elem offset
    const unsigned short* gA0 = An + (size_t)(m0 + (2*wav+0)*16 + la)*lda + ka;
    const unsigned short* gA1 = An + (size_t)(m0 + (2*wav+1)*16 + la)*lda + ka;
    short* lA0 = Al + (size_t)((2*wav+0)*64)*8;
    short* lA1 = Al + (size_t)((2*wav+1)*64)*8;
    short* lB0 = Bl + (size_t)((2*wav+0)*64)*8;
    short* lB1 = Bl + (size_t)((2*wav+1)*64)*8;
    const unsigned short* BnU = (const unsigned short*)Bv + (size_t)n*bn_stride;
    const int cb0 = j0 + (2*wav+0)*16 + la;
    const int cb1 = j0 + (2*wav+1)*16 + la;
    const unsigned short* gB0 = nullptr;
    const unsigned short* gB1 = nullptr;
    if (BMODE == 0) {
        gB0 = BnU + (size_t)cb0*ldb + ka;
        gB1 = BnU + (size_t)cb1*ldb + ka;
    } else if (BMODE == 1 || BMODE == 3) {
        gB0 = BnU + (size_t)cb0*128 + ka;
        gB1 = BnU + (size_t)cb1*128 + ka;
    }
    // reg-staging ids (BMODE 4/5)
    const int scol = tid & 127, skq = tid >> 7;
    const int bcol = j0 + scol;
    const int ecol = (BMODE == 5) ? ((bcol & 127)*25 + (bcol >> 7)) : bcol;

    f32x4 acc[2][8];
    #pragma unroll
    for (int i = 0; i < 2; ++i)
        #pragma unroll
        for (int c = 0; c < 8; ++c) acc[i][c] = (f32x4){0.f,0.f,0.f,0.f};

    for (int k0 = 0; k0 < K; k0 += 32) {
        bf16x8 b0r, b1r;
        if (BMODE == 4 || BMODE == 5) {   // fp32 -> bf16 regs, issue pre-barrier
            const float* Bf = (const float*)Bv + (size_t)n*bn_stride;
            #pragma unroll
            for (int j = 0; j < 8; ++j)
                b0r[j] = (short)f2bf(Bf[(size_t)(k0 + skq*16 + j)*ldb + ecol]);
            #pragma unroll
            for (int j = 0; j < 8; ++j)
                b1r[j] = (short)f2bf(Bf[(size_t)(k0 + skq*16 + 8 + j)*ldb + ecol]);
        }

        __syncthreads();   // previous tile fully consumed
        gload16(gA0 + k0, lA0);
        gload16(gA1 + k0, lA1);
        if (BMODE == 0) {
            gload16(gB0 + k0, lB0);
            gload16(gB1 + k0, lB1);
        } else if (BMODE == 1) {
            const int off = ((k0 >> 7) - 3)*3200 + (k0 & 127);
            gload16(gB0 + off, lB0);
            gload16(gB1 + off, lB1);
        } else if (BMODE == 3) {
            const int off = (k0 >> 7)*409600 + (k0 & 127);
            gload16(gB0 + off, lB0);
            gload16(gB1 + off, lB1);
        } else {   // BMODE 4/5 reg staging
            short* Bp = Bl + ((size_t)((scol>>4)*64 + (scol&15) + 32*skq))*8;
            *(bf16x8*)Bp = b0r;
            *(bf16x8*)(Bp + 128) = b1r;
        }
        __syncthreads();   // implicit vmcnt(0) drains gloads -> tile ready

        bf16x8 afr[2], bfr[8];
        afr[0] = *(const bf16x8*)(Al + ((size_t)((2*wav+0)*64 + lane))*8);
        afr[1] = *(const bf16x8*)(Al + ((size_t)((2*wav+1)*64 + lane))*8);
        #pragma unroll
        for (int c = 0; c < 8; ++c)
            bfr[c] = *(const bf16x8*)(Bl + ((size_t)(c*64 + lane))*8);
        #pragma unroll
        for (int i = 0; i < 2; ++i)
            #pragma unroll
            for (int c = 0; c < 8; ++c)
                acc[i][c] = __builtin_amdgcn_mfma_f32_16x16x32_bf16(
                    afr[i], bfr[c], acc[i][c], 0, 0, 0);
    }

    // ---- epilogues ----
    if (DMODE == 1) {
        // LDS-transposed flush: tile [col][128] is contiguous 32KB in global.
        // Each pass: 64 cols x 128 m in Ot; drain = 1024 chunks of 8 shorts.
        #pragma unroll
        for (int p = 0; p < 2; ++p) {
            #pragma unroll
            for (int i = 0; i < 2; ++i) {
                const int mbase = (2*wav + i)*16 + lq*4;   // m0==0 (M=128)
                #pragma unroll
                for (int cq = 0; cq < 4; ++cq) {
                    const int ct = 4*p + cq;
                    const int col = j0 + ct*16 + l16;
                    short4v pk;
                    #pragma unroll
                    for (int r = 0; r < 4; ++r) {
                        const int mg = mbase + r;
                        const size_t addr = (size_t)mg*ldd + col
                                          + (size_t)n*dn_stride;
                        float val = acc[i][ct][r] + (bias ? bias[mg] : 0.f);
                        if (gg) {
                            val = val*(gg[mg]*BN_INV) + bb[mg] + resp[addr];
                            val = val > 0.f ? val : 0.1f*val;
                        }
                        if (OM != 1) D[addr] = val;
                        pk[r] = (short)f2bf(val);
                    }
                    *(short4v*)(Ot + (ct*16 + l16 - p*64)*136 + mbase) = pk;
                }
            }
            __syncthreads();
            #pragma unroll
            for (int j = 0; j < 4; ++j) {
                int idx = j*256 + tid;
                int cl = idx >> 4, m8 = (idx & 15)*8;   // R9 FIX (was >>3, &7)
                bf16x8 vv = *(const bf16x8*)(Ot + cl*136 + m8);
                *(bf16x8*)(Dbf + (size_t)(j0 + p*64 + cl)*128 + m8
                           + (size_t)n*dbfn) = vv;
            }
            if (p == 0) __syncthreads();
        }
    } else {
        #pragma unroll
        for (int i = 0; i < 2; ++i) {
            const int mbase = m0 + (2*wav + i)*16 + lq*4;
            #pragma unroll
            for (int ct = 0; ct < 8; ++ct) {
                const int col = j0 + ct*16 + l16;
                if (DMODE == 0) {
                    #pragma unroll
                    for (int r = 0; r < 4; ++r) {
                        const int mg = mbase + r;
                        if (mg < M) {
                            const size_t addr = (size_t)mg*ldd + col
                                              + (size_t)n*dn_stride;
                            float val = acc[i][ct][r] + (bias ? bias[mg] : 0.f);
                            if (gg) {
                                val = val*(gg[mg]*BN_INV) + bb[mg] + resp[addr];
                                val = val > 0.f ? val : 0.1f*val;
                            }
                            if (OM != 1) D[addr] = val;
                            if (OM >= 1) Dbf[addr] = f2bf(val);
                        }
                    }
                } else if (DMODE == 2) {  // t1 v-major: c across lanes (32B runs)
                    const int v = j0 >> 7;
                    const int c = ct*16 + l16;
                    const float bi = bias ? bias[c] : 0.f;
                    float gv = 0.f, b2 = 0.f;
                    if (gg) { gv = gg[c]*BN_INV; b2 = bb[c]; }
                    #pragma unroll
                    for (int r = 0; r < 4; ++r) {
                        const int u = mbase + r;
                        float val = acc[i][ct][r] + bi;
                        if (gg) {
                            val = val*gv + b2 + resp[(size_t)c*3200
                                   + (size_t)u*25 + v + (size_t)n*dn_stride];
                            val = val > 0.f ? val : 0.1f*val;
                        }
                        Dbf[(size_t)(u*25 + v)*128 + c + (size_t)n*dbfn]
                            = f2bf(val);
                    }
                } else {   // DMODE 3: tmp v-major: t across lanes (32B runs)
                    const int v = j0 >> 7;
                    const int t = ct*16 + l16;
                    #pragma unroll
                    for (int r = 0; r < 4; ++r) {
                        const int mg = mbase + r;
                        float val = acc[i][ct][r] + (bias ? bias[mg] : 0.f);
                        Dbf[(size_t)(mg >> 7)*409600
                            + (size_t)((v << 7) + (mg & 127))*128 + t
                            + (size_t)n*dbfn] = f2bf(val);
                    }
                }
            }
        }
    }
}

// weight prep: convert (and permute) all weights to bf16 in WB
__global__ void k_prep(const float* __restrict__ wis, const float* __restrict__ wos,
                       const float* __restrict__ wfs, const float* __restrict__ wit,
                       const float* __restrict__ wot, const float* __restrict__ wft,
                       const float* __restrict__ wtc, unsigned short* __restrict__ W) {
    int i = blockIdx.x*256 + threadIdx.x;
    if (i < 24576) { W[i] = f2bf(wis[i]); return; }          i -= 24576;
    if (i < 49152) { W[24576 + i] = f2bf(wos[i]); return; }  i -= 49152;
    if (i < 16384) { W[73728 + i] = f2bf(wfs[i]); return; }  i -= 16384;
    if (i < 32768) { W[90112 + i] = f2bf(wit[i]); return; }  i -= 32768;
    if (i < 65536) { // [(h*128+o)][c] <- wot[o][h*128+c]
        int ho = i >> 7, c = i & 127; int h = ho >> 7, o = ho & 127;
        W[122880 + i] = f2bf(wot[o*512 + h*128 + c]); return; } i -= 65536;
    if (i < 16384) { W[188416 + i] = f2bf(wft[i]); return; } i -= 16384;
    if (i < 114688) { // [o][kidx*128+c] <- wtc[(o*128+c)*7 + kidx]
        int o = i / 896; int r = i - o*896; int kidx = r >> 7, c = r & 127;
        W[204800 + i] = f2bf(wtc[(o*128 + c)*7 + kidx]); }
}

// zero the TCN pad margins: per n, shorts [0,9600) and [419200,428800).
// MUST run after the t1 GEMM (TOUTBP overlaps Y2BF and TMPB; t1 is the
// last TMPB reader — R5/R6 bug history).
__global__ void k_zpad(unsigned short* __restrict__ p) {
    int i = blockIdx.x*256 + threadIdx.x;     // 76800 threads x 8 shorts
    if (i >= 76800) return;
    int chunk = i*8;
    int n = chunk / 19200;
    int r = chunk - n*19200;
    size_t addr = (size_t)n*428800 + (size_t)(r < 9600 ? r : 419200 + (r - 9600));
    *(bf16x8*)(p + addr) = (bf16x8){0,0,0,0,0,0,0,0};
}

// spatial attention: atts_bf = att0 + tanh(q.k/32)*alpha  (reads bf16 qk)
__global__ void k_att_s(const unsigned short* __restrict__ qk,
                        const float* __restrict__ att0,
                        const float* __restrict__ alphas,
                        unsigned short* __restrict__ att) {
    int b = blockIdx.x;
    int n = b / (3*Tt); int rem = b - n*(3*Tt); int s = rem / Tt; int t = rem - s*Tt;
    __shared__ float qs[32*Vv], ks[32*Vv];
    const unsigned short* qp = qk + (size_t)n*614400 + (size_t)(s*32)*3200 + t*25;
    const unsigned short* kp = qk + (size_t)n*614400 + (size_t)(96 + s*32)*3200 + t*25;
    for (int i = threadIdx.x; i < 32*Vv; i += 256) {
        int c = i / Vv, v = i - c*Vv;
        qs[i] = bf2f(qp[(size_t)c*3200 + v]);
        ks[i] = bf2f(kp[(size_t)c*3200 + v]);
    }
    __syncthreads();
    float alpha = alphas[s];
    for (int i = threadIdx.x; i < Vv*Vv; i += 256) {
        int u = i / Vv, v = i - u*Vv;
        float a = 0.f;
        #pragma unroll
        for (int c = 0; c < 32; ++c) a += qs[c*Vv + u] * ks[c*Vv + v];
        att[(size_t)n*240000 + (size_t)s*80000 + (size_t)t*625 + i] =
            f2bf(att0[s*625 + i] + tanhf(a * (1.f/32.f)) * alpha);
    }
}

// =====================================================================
// MFMA spatial einsum -> Y2 TRANSPOSED: y2T[col=t*25+v][s*128+c]
// =====================================================================
__global__ __launch_bounds__(256, 2) void k_eins_mfma(
    const float* __restrict__ X, const unsigned short* __restrict__ att,
    unsigned short* __restrict__ y2)
{
    __shared__ short Xf[128*128];     // [c][tl*32+u] bf16, swizzled (32KB)
    __shared__ short Bf[7*4*64*8];    // frag [nt][ks][lane][j] (28KB)

    const int n  = blockIdx.x >> 5;
    const int t0 = (blockIdx.x & 31) * 4;
    const int tid = threadIdx.x;
    const int wav = tid >> 6, lane = tid & 63;
    const int lq = lane >> 4, l16 = lane & 15;

    for (int i = tid; i < 7*4*64; i += 256)
        *(bf16x8*)(Bf + (size_t)i*8) = (bf16x8){0,0,0,0,0,0,0,0};

    const float* xp = X + (size_t)n*409600;
    for (int i = tid; i < 8192; i += 256) {
        int u2 = (i & 15)*2, tl = (i >> 4) & 3, c = i >> 6;
        float f0 = 0.f, f1 = 0.f;
        if (u2 < 25) {
            const float* p = xp + (size_t)c*3200 + (t0 + tl)*25 + u2;
            f0 = p[0];
            if (u2 < 24) f1 = p[1];
        }
        unsigned pk = (unsigned)f2bf(f0) | ((unsigned)f2bf(f1) << 16);
        int byte = (i*4) ^ ((c & 7) << 4);
        *(unsigned*)((char*)Xf + byte) = pk;
    }
    __syncthreads();

    bf16x8 afr[2][4];
    #pragma unroll
    for (int i = 0; i < 2; ++i) {
        const int c = (2*wav + i)*16 + l16;
        #pragma unroll
        for (int ks = 0; ks < 4; ++ks) {
            int byte = ((c*128 + ks*32 + lq*8)*2) ^ ((c & 7) << 4);
            afr[i][ks] = *(const bf16x8*)((const char*)Xf + byte);
        }
    }

    for (int s = 0; s < 3; ++s) {
        const unsigned short* ap = att + (size_t)n*240000 + (size_t)s*80000
                                       + (size_t)t0*625;
        for (int j = tid; j < 2500; j += 256) {
            int tl = j / 625, r = j - tl*625;
            int u = r / 25, v = r - u*25;
            int col = tl*25 + v;
            int l = ((u >> 3) << 4) | (col & 15);
            int nt = col >> 4;
            Bf[(size_t)((nt*4 + tl)*64 + l)*8 + (u & 7)] = (short)ap[j];
        }
        __syncthreads();

        f32x4 acc[2][7];
        #pragma unroll
        for (int i = 0; i < 2; ++i)
            #pragma unroll
            for (int nt = 0; nt < 7; ++nt) acc[i][nt] = (f32x4){0.f,0.f,0.f,0.f};

        #pragma unroll
        for (int ks = 0; ks < 4; ++ks) {
            bf16x8 bfr[7];
            #pragma unroll
            for (int nt = 0; nt < 7; ++nt)
                bfr[nt] = *(const bf16x8*)(Bf + (size_t)((nt*4 + ks)*64 + lane)*8);
            #pragma unroll
            for (int i = 0; i < 2; ++i)
                #pragma unroll
                for (int nt = 0; nt < 7; ++nt)
                    acc[i][nt] = __builtin_amdgcn_mfma_f32_16x16x32_bf16(
                        afr[i][ks], bfr[nt], acc[i][nt], 0, 0, 0);
        }

        // transposed write: y2T[(t0*25+col)*384 + s*128 + row..row+3]
        unsigned short* yb = y2 + (size_t)n*1228800;
        #pragma unroll
        for (int i = 0; i < 2; ++i) {
            const int row = (2*wav + i)*16 + lq*4;
            #pragma unroll
            for (int nt = 0; nt < 7; ++nt) {
                const int col = nt*16 + l16;
                if (col < 100) {
                    short4v pk;
                    #pragma unroll
                    for (int r = 0; r < 4; ++r) pk[r] = (short)f2bf(acc[i][nt][r]);
                    *(short4v*)(yb + (size_t)(t0*25 + col)*384 + s*128 + row) = pk;
                }
            }
        }
        __syncthreads();
    }
}

// xbarT[n][t*128 + c] = mean_v sout  (k-contiguous for qkt GEMM)
__global__ void k_mean(const float* __restrict__ X, unsigned short* __restrict__ xb) {
    int idx = blockIdx.x*256 + threadIdx.x;
    if (idx >= Nn*Cc*Tt) return;
    const float* p = X + (size_t)idx*25;
    float s = 0.f;
    #pragma unroll
    for (int v = 0; v < Vv; ++v) s += p[v];
    int n = idx >> 14, rem = idx & 16383, c = rem >> 7, t = rem & 127;
    xb[(size_t)n*16384 + (size_t)t*128 + c] = f2bf(s * (1.f/25.f));
}

// temporal attention: attb_bf[n][u][(h*128+t)] = mask*alpha*tanh(dot/32)
__global__ void k_att_t(const float* __restrict__ qkt, const float* __restrict__ af,
                        const float* __restrict__ ab, unsigned short* __restrict__ attb) {
    int n = blockIdx.x >> 2, h = blockIdx.x & 3;
    __shared__ float qs[32*Tt], ks[32*Tt];
    const float* qp = qkt + (size_t)n*32768 + (size_t)(h*32)*128;
    const float* kp = qkt + (size_t)n*32768 + (size_t)(128 + h*32)*128;
    for (int i = threadIdx.x; i < 32*Tt; i += 256) { qs[i] = qp[i]; ks[i] = kp[i]; }
    __syncthreads();
    float alpha = (h < 2) ? af[h] : ab[h-2];
    for (int i = threadIdx.x; i < Tt*Tt; i += 256) {
        int u = i >> 7, t = i & 127;
        bool keep = (h < 2) ? (t >= u) : (t <= u);
        float val = 0.f;
        if (keep) {
            float a = 0.f;
            #pragma unroll
            for (int c = 0; c < 32; ++c) a += qs[c*Tt + t] * ks[c*Tt + u];
            val = tanhf(a * (1.f/32.f)) * alpha;
        }
        attb[(size_t)n*65536 + (size_t)u*512 + h*128 + t] = f2bf(val);
    }
}

extern "C" void kernel_launch(void* const* d_in, const int* in_sizes, int n_in,
                              void* d_out, int out_size, void* d_ws, size_t ws_size,
                              hipStream_t stream) {
    const float* x       = (const float*)d_in[0];
    const float* w_in_s  = (const float*)d_in[1];
    const float* b_in_s  = (const float*)d_in[2];
    const float* att0s   = (const float*)d_in[3];
    const float* alphas  = (const float*)d_in[4];
    const float* w_out_s = (const float*)d_in[5];
    const float* b_out_s = (const float*)d_in[6];
    const float* g_out_s = (const float*)d_in[7];
    const float* be_out_s= (const float*)d_in[8];
    const float* w_ff_s  = (const float*)d_in[9];
    const float* b_ff_s  = (const float*)d_in[10];
    const float* g_ff_s  = (const float*)d_in[11];
    const float* be_ff_s = (const float*)d_in[12];
    const float* w_in_t  = (const float*)d_in[13];
    const float* b_in_t  = (const float*)d_in[14];
    const float* alphat_f= (const float*)d_in[15];
    const float* alphat_b= (const float*)d_in[16];
    const float* w_out_t = (const float*)d_in[17];
    const float* b_out_t = (const float*)d_in[18];
    const float* g_out_t = (const float*)d_in[19];
    const float* be_out_t= (const float*)d_in[20];
    const float* w_ff_t  = (const float*)d_in[21];
    const float* b_ff_t  = (const float*)d_in[22];
    const float* g_ff_t  = (const float*)d_in[23];
    const float* be_ff_t = (const float*)d_in[24];
    const float* w_tcn   = (const float*)d_in[25];
    const float* b_tcn   = (const float*)d_in[26];
    const float* g_tcn   = (const float*)d_in[27];
    const float* be_tcn  = (const float*)d_in[28];

    float* ws = (float*)d_ws;
    unsigned short* WB    = (unsigned short*)ws;
    unsigned short* QKBF  = (unsigned short*)(ws + 200000);
    unsigned short* S1BF  = (unsigned short*)(ws + 200000);   // transposed
    unsigned short* ATSB  = (unsigned short*)(ws + 10030400);
    unsigned short* Y2BF  = (unsigned short*)(ws + 13870400); // transposed
    unsigned short* TOUTBP= (unsigned short*)(ws + 23710000); // padded base
    unsigned short* TOUTB = TOUTBP + 9600;                    // e=0 of n=0
    float*          SOUT  = ws + 33531200;
    unsigned short* ATTB  = (unsigned short*)(ws + 200000);
    unsigned short* XBARB = (unsigned short*)(ws + 1300000);  // transposed
    float*          QKT   = ws + 1600000;
    unsigned short* TMPB  = (unsigned short*)(ws + 2700000);  // [h][(v,o)][t]
    unsigned short* T1BF  = (unsigned short*)(ws + 46638400); // transposed
    float*          TOUT  = ws + 2700000;
    float* out = (float*)d_out;

    unsigned short* wbis = WB;
    unsigned short* wbos = WB + 24576;
    unsigned short* wbfs = WB + 73728;
    unsigned short* wbit = WB + 90112;
    unsigned short* wbot = WB + 122880;
    unsigned short* wbft = WB + 188416;
    unsigned short* wbtc = WB + 204800;

    dim3 blk(256);
    const float* NUL = nullptr;

    k_prep<<<1248, blk, 0, stream>>>(w_in_s, w_out_s, w_ff_s, w_in_t,
                                     w_out_t, w_ff_t, w_tcn, WB);

    // ---- spatial ----
    // qk_bf = W_in_s @ x + b   (M=192, K=128, B=x fp32, D row-major)
    gemm_k<4,0,1><<<1600, blk, 0, stream>>>(
        wbis, x, nullptr, QKBF, NUL, b_in_s, NUL, NUL,
        192, 128, 128, 3200, 3200, 0L, 409600L, 614400L, 614400L, 25, 50);
    k_att_s<<<Nn*3*Tt, blk, 0, stream>>>(QKBF, att0s, alphas, ATSB);
    k_eins_mfma<<<dim3(Nn*32), blk, 0, stream>>>(x, ATSB, Y2BF);
    // s1T = lrelu(x + bn(W_out_s @ y2T + b))   (B=Y2T ldb=384, LDS flush)
    gemm_k<0,1,1><<<800, blk, 0, stream>>>(
        wbos, Y2BF, nullptr, S1BF, x, b_out_s, g_out_s, be_out_s,
        128, 384, 384, 384, 3200, 0L, 1228800L, 409600L, 409600L, 25, 25);
    // sout = lrelu(x + bn(W_ff_s @ s1T + b))   (D=SOUT fp32 row-major)
    gemm_k<0,0,0><<<800, blk, 0, stream>>>(
        wbfs, S1BF, SOUT, nullptr, x, b_ff_s, g_ff_s, be_ff_s,
        128, 128, 128, 128, 3200, 0L, 409600L, 409600L, 409600L, 25, 25);

    // ---- temporal ----
    k_mean<<<2048, blk, 0, stream>>>(SOUT, XBARB);
    // qkt = W_in_t @ xbarT + b   (M=256, B=XBARB_T ldb=128, D row-major)
    gemm_k<0,0,0><<<64, blk, 0, stream>>>(
        wbit, XBARB, QKT, nullptr, NUL, b_in_t, NUL, NUL,
        256, 128, 128, 128, 128, 0L, 16384L, 32768L, 32768L, 1, 2);
    k_att_t<<<Nn*4, blk, 0, stream>>>(QKT, alphat_f, alphat_b, ATTB);
    // tmp[h][(v*128+o)][t] = W_out_t_perm @ sout  (BMODE5 v-major, DMODE3)
    gemm_k<5,3,1><<<3200, blk, 0, stream>>>(
        wbot, SOUT, nullptr, TMPB, NUL, NUL, NUL, NUL,
        512, 128, 128, 3200, 3200, 0L, 409600L, 1638400L, 1638400L, 25, 100);
    // t1T = lrelu(sout + bn(att @ tmp + b))  (BMODE3, DMODE2 v-major)
    gemm_k<3,2,1><<<800, blk, 0, stream>>>(
        ATTB, TMPB, nullptr, T1BF, SOUT, b_out_t, g_out_t, be_out_t,
        128, 512, 512, 0, 3200, 65536L, 1638400L, 409600L, 409600L, 25, 25);
    // TMPB now dead -> safe to zero TCN pad margins (TOUTBP overlaps TMPB/Y2)
    k_zpad<<<300, blk, 0, stream>>>(TOUTBP);
    // tout fp32 + toutbT = lrelu(sout + bn(W_ff_t @ t1T + b))  (DMODE1 OM2)
    gemm_k<0,1,2><<<800, blk, 0, stream>>>(
        wbft, T1BF, TOUT, TOUTB, SOUT, b_ff_t, g_ff_t, be_ff_t,
        128, 128, 128, 128, 3200, 0L, 409600L, 409600L, 428800L, 25, 25);

    // ---- TCN ----
    // out = lrelu(tout + bn(conv7 @ toutbT + b))  (K=896, BMODE1 padded)
    gemm_k<1,0,0><<<800, blk, 0, stream>>>(
        wbtc, TOUTB, out, nullptr, TOUT, b_tcn, g_tcn, be_tcn,
        128, 896, 896, 0, 3200, 0L, 428800L, 409600L, 409600L, 25, 25);
}

// Round 10
// 809.301 us; speedup vs baseline: 1.2425x; 1.1022x over previous
//
#include <hip/hip_runtime.h>
#include <cstddef>

#define Nn 32
#define Cc 128
#define Tt 128
#define Vv 25
#define BN_INV 0.9999950000374997f

// ---------------- workspace layout (float offsets), max 53,192,000 ----------
// WB (bf16 weights)    @ 0          (159,744 f as sh)
// QKBF  [n][192][3200] @ 200,000    (9,830,400)   dead after att_s
// S1BF  [n][128][3200] @ 200,000    (reuse, qk dead)
// ATSB  [n][3][t][625] @ 10,030,400 (3,840,000)
// Y2BF  [n][384][3200] @ 13,870,400 (19,660,800)
// SOUT  fp32           @ 33,531,200 (13,107,200)  live til TCN
// ATTB  [n][u][512]    @ 200,000    (reuse, s1 dead)
// XBARB                @ 1,300,000
// QKT   fp32           @ 1,600,000  (1,048,576)
// TMPB  [n][512][3200] @ 2,700,000  (26,214,400)  dead after t1 GEMM
// T1BF  [n][128][3200] @ 46,638,400 (6,553,600)
// TOUT  fp32           @ 2,700,000  (13,107,200, tmp dead)
// TOUTB @ 15,810,000   (6,553,600)
// HISTORY: R3 explicit dbuf pipeline REGRESSED (occupancy). R4 = XCD swizzle
// (whole n per XCD; TCN FETCH 126->39.5MB) = 710us BEST. R5-R9 gload +
// transposed-layout direction netted -180us (scatter whack-a-mole: fixing
// store-amp created read-scatter) -> REVERTED to R4 structure.
// R10: single change vs R4 — K-block 32->64. Halves the per-iteration
// vmcnt(0)+barrier drains (TCN 28->14 iters), doubles MFMA per drain.
// LDS 16->32KB (still >= grid-limited residency at 800-block grids).

typedef __attribute__((ext_vector_type(8))) short bf16x8;
typedef __attribute__((ext_vector_type(4))) float f32x4;

__device__ __forceinline__ unsigned short f2bf(float f) {
    union { float f; unsigned u; } x; x.f = f;
    return (unsigned short)((x.u + 0x7FFFu + ((x.u >> 16) & 1u)) >> 16);
}
__device__ __forceinline__ float bf2f(unsigned short s) {
    union { unsigned u; float f; } x; x.u = ((unsigned)s) << 16;
    return x.f;
}

// =====================================================================
// MFMA bf16 GEMM, tile 128x128, 256 thr = 4 waves, K-block 64 (2 sub-blocks
// of 32 staged per barrier pair; R1/R4 fragment layout per sub-block).
// 1D grid, nwg % 8 == 0. XCD swizzle: w = (b&7)*(nwg>>3) + (b>>3);
// n = w/gxn -> whole n's per XCD so per-n B/resp slices stay L2-resident.
// A: bf16 row-major [M][lda] @ A + n*an_stride
// BMODE 0: bf16 row-major [K][ldb]
// BMODE 4: fp32 row-major [K][ldb] (convert in loader)
// BMODE 1: TCN shifted: k=(kidx,c): B[k][col] = Bn[c*3200 + col + (kidx-3)*25]
// BMODE 3: tein: k=(h,t), col=(o,v): B[k][col] = Bn[h*409600 + o*3200 + t*25 + v]
// DMODE 0: addr = m*ldd + col ; DMODE 2: m=u, col=(c,v): addr = c*3200+u*25+v
// OM: 0 fp32 D only, 1 bf16 Dbf only, 2 both
// epilogue: val = acc (+bias); if(gg): val = val*g*BN_INV + bb + resp; lrelu
// =====================================================================

// fill BQ[0..16) with B elems for k = K0 + j (K0 already includes skq*16)
#define BFETCH(K0, BQ)                                                         \
    {                                                                          \
        if (BMODE == 0) {                                                      \
            const unsigned short* Bn = (const unsigned short*)Bv               \
                                     + (size_t)n*bn_stride;                    \
            _Pragma("unroll")                                                  \
            for (int j = 0; j < 16; ++j)                                       \
                (BQ)[j] = Bn[(size_t)((K0) + j)*ldb + bcol];                   \
        } else if (BMODE == 4) {                                               \
            const float* Bf = (const float*)Bv + (size_t)n*bn_stride;          \
            _Pragma("unroll")                                                  \
            for (int j = 0; j < 16; ++j)                                       \
                (BQ)[j] = f2bf(Bf[(size_t)((K0) + j)*ldb + bcol]);             \
        } else if (BMODE == 1) {                                               \
            const unsigned short* Bn = (const unsigned short*)Bv               \
                                     + (size_t)n*bn_stride;                    \
            int kb = (K0);                                                     \
            int kidx = kb >> 7, c0 = kb & 127;                                 \
            int e = bcol + (kidx - 3)*25;                                      \
            bool ok = ((unsigned)e < 3200u);                                   \
            _Pragma("unroll")                                                  \
            for (int j = 0; j < 16; ++j)                                       \
                (BQ)[j] = ok ? Bn[(size_t)(c0 + j)*3200 + e]                   \
                             : (unsigned short)0;                              \
        } else { /* BMODE 3 */                                                 \
            const unsigned short* Bn = (const unsigned short*)Bv               \
                                     + (size_t)n*bn_stride;                    \
            int kb = (K0);                                                     \
            int h = kb >> 7, t0b = kb & 127;                                   \
            const unsigned short* bp = Bn + (size_t)h*409600 + (size_t)bo*3200 \
                                          + (size_t)t0b*25 + bv_;              \
            _Pragma("unroll")                                                  \
            for (int j = 0; j < 16; ++j) (BQ)[j] = bp[j*25];                   \
        }                                                                      \
    }

template<int BMODE, int DMODE, int OM>
__global__ __launch_bounds__(256, 2) void gemm_k(
    const unsigned short* __restrict__ A, const void* __restrict__ Bv,
    float* __restrict__ D, unsigned short* __restrict__ Dbf,
    const float* __restrict__ resp, const float* __restrict__ bias,
    const float* __restrict__ gg, const float* __restrict__ bb,
    int M, int K, int lda, int ldb, int ldd,
    long an_stride, long bn_stride, long dn_stride, int gn, int gxn)
{
    __shared__ short Al[2*8*64*8];   // 16KB: 2 k-sub-blocks x 8 m-frags
    __shared__ short Bl[2*8*64*8];   // 16KB: 2 k-sub-blocks x 8 col-frags

    // ---- XCD-aware bijective swizzle (nwg % 8 == 0 guaranteed) ----
    const int nwg = gridDim.x;
    const int b   = blockIdx.x;
    const int w   = (b & 7)*(nwg >> 3) + (b >> 3);
    const int n   = w / gxn;
    const int rem = w - n*gxn;
    const int mt  = rem / gn;
    const int nt  = rem - mt*gn;
    const int m0 = mt*128;
    const int j0 = nt*128;

    const unsigned short* An = A + (size_t)n*an_stride;

    const int tid = threadIdx.x;
    const int wav = tid >> 6, lane = tid & 63;
    const int lq = lane >> 4, l16 = lane & 15;

    const int sm  = tid >> 1, skh = tid & 1;      // A staging: row, k-half
    const int scol = tid & 127, skq = tid >> 7;   // B staging: col, k-half
    const int bcol = j0 + scol;

    int bo = 0, bv_ = 0;
    if (BMODE == 3) { bo = bcol/25; bv_ = bcol - 25*bo; }

    f32x4 acc[2][8];
    #pragma unroll
    for (int i = 0; i < 2; ++i)
        #pragma unroll
        for (int c = 0; c < 8; ++c) acc[i][c] = (f32x4){0.f,0.f,0.f,0.f};

    for (int k0 = 0; k0 < K; k0 += 64) {
        // ---- A fetch: 32 bf16, row m0+sm, k in [k0+skh*16,+16) u [+32,..) --
        bf16x8 a0 = (bf16x8){0,0,0,0,0,0,0,0}, a1 = a0, a2 = a0, a3 = a0;
        {
            int mg = m0 + sm;
            if (mg < M) {
                const unsigned short* ap = An + (size_t)mg*lda + k0 + skh*16;
                a0 = *(const bf16x8*)ap;
                a1 = *(const bf16x8*)(ap + 8);
                a2 = *(const bf16x8*)(ap + 32);
                a3 = *(const bf16x8*)(ap + 40);
            }
        }
        // ---- B fetch: 32 elems, col bcol, two 16-k segments ----
        unsigned short bq[16], bq2[16];
        BFETCH(k0 + skq*16, bq);
        BFETCH(k0 + 32 + skq*16, bq2);

        __syncthreads();   // previous tile consumed
        {
            short* Ap = Al + ((size_t)((sm>>4)*64 + (sm&15) + 32*skh))*8;
            *(bf16x8*)Ap = a0;
            *(bf16x8*)(Ap + 128) = a1;          // +16 lane-slots
            *(bf16x8*)(Ap + 4096) = a2;         // sub-block 1
            *(bf16x8*)(Ap + 4096 + 128) = a3;
        }
        {
            short* Bp = Bl + ((size_t)((scol>>4)*64 + (scol&15) + 32*skq))*8;
            bf16x8 p0, p1, p2, p3;
            #pragma unroll
            for (int j = 0; j < 8; ++j) {
                p0[j] = (short)bq[j];  p1[j] = (short)bq[8+j];
                p2[j] = (short)bq2[j]; p3[j] = (short)bq2[8+j];
            }
            *(bf16x8*)Bp = p0;
            *(bf16x8*)(Bp + 128) = p1;
            *(bf16x8*)(Bp + 4096) = p2;
            *(bf16x8*)(Bp + 4096 + 128) = p3;
        }
        __syncthreads();

        #pragma unroll
        for (int h = 0; h < 2; ++h) {
            bf16x8 afr[2], bfr[8];
            afr[0] = *(const bf16x8*)(Al + h*4096
                                      + ((size_t)((2*wav+0)*64 + lane))*8);
            afr[1] = *(const bf16x8*)(Al + h*4096
                                      + ((size_t)((2*wav+1)*64 + lane))*8);
            #pragma unroll
            for (int c = 0; c < 8; ++c)
                bfr[c] = *(const bf16x8*)(Bl + h*4096
                                          + ((size_t)(c*64 + lane))*8);
            #pragma unroll
            for (int i = 0; i < 2; ++i)
                #pragma unroll
                for (int c = 0; c < 8; ++c)
                    acc[i][c] = __builtin_amdgcn_mfma_f32_16x16x32_bf16(
                        afr[i], bfr[c], acc[i][c], 0, 0, 0);
        }
    }

    // ---- epilogue: row = m0+(2w+i)*16+lq*4+r ; col = j0+ct*16+l16 ----
    #pragma unroll
    for (int i = 0; i < 2; ++i) {
        const int mbase = m0 + (2*wav + i)*16 + lq*4;
        #pragma unroll
        for (int ct = 0; ct < 8; ++ct) {
            const int col = j0 + ct*16 + l16;
            if (DMODE == 0) {
                #pragma unroll
                for (int r = 0; r < 4; ++r) {
                    const int mg = mbase + r;
                    if (mg < M) {
                        const size_t addr = (size_t)mg*ldd + col + (size_t)n*dn_stride;
                        float val = acc[i][ct][r] + (bias ? bias[mg] : 0.f);
                        if (gg) {
                            val = val*(gg[mg]*BN_INV) + bb[mg] + resp[addr];
                            val = val > 0.f ? val : 0.1f*val;
                        }
                        if (OM != 1) D[addr] = val;
                        if (OM >= 1) Dbf[addr] = f2bf(val);
                    }
                }
            } else { // DMODE 2
                const int c = col/25, v = col - 25*c;
                const float bi = bias ? bias[c] : 0.f;
                float gv = 0.f, b2 = 0.f;
                if (gg) { gv = gg[c]*BN_INV; b2 = bb[c]; }
                #pragma unroll
                for (int r = 0; r < 4; ++r) {
                    const int u = mbase + r;
                    const size_t addr = (size_t)c*3200 + (size_t)u*25 + v
                                      + (size_t)n*dn_stride;
                    float val = acc[i][ct][r] + bi;
                    if (gg) {
                        val = val*gv + b2 + resp[addr];
                        val = val > 0.f ? val : 0.1f*val;
                    }
                    if (OM != 1) D[addr] = val;
                    if (OM >= 1) Dbf[addr] = f2bf(val);
                }
            }
        }
    }
}

// weight prep: convert (and permute) all weights to bf16 in WB
__global__ void k_prep(const float* __restrict__ wis, const float* __restrict__ wos,
                       const float* __restrict__ wfs, const float* __restrict__ wit,
                       const float* __restrict__ wot, const float* __restrict__ wft,
                       const float* __restrict__ wtc, unsigned short* __restrict__ W) {
    int i = blockIdx.x*256 + threadIdx.x;
    if (i < 24576) { W[i] = f2bf(wis[i]); return; }          i -= 24576;
    if (i < 49152) { W[24576 + i] = f2bf(wos[i]); return; }  i -= 49152;
    if (i < 16384) { W[73728 + i] = f2bf(wfs[i]); return; }  i -= 16384;
    if (i < 32768) { W[90112 + i] = f2bf(wit[i]); return; }  i -= 32768;
    if (i < 65536) { // [(h*128+o)][c] <- wot[o][h*128+c]
        int ho = i >> 7, c = i & 127; int h = ho >> 7, o = ho & 127;
        W[122880 + i] = f2bf(wot[o*512 + h*128 + c]); return; } i -= 65536;
    if (i < 16384) { W[188416 + i] = f2bf(wft[i]); return; } i -= 16384;
    if (i < 114688) { // [o][kidx*128+c] <- wtc[(o*128+c)*7 + kidx]
        int o = i / 896; int r = i - o*896; int kidx = r >> 7, c = r & 127;
        W[204800 + i] = f2bf(wtc[(o*128 + c)*7 + kidx]); }
}

// spatial attention: atts_bf = att0 + tanh(q.k/32)*alpha  (reads bf16 qk)
__global__ void k_att_s(const unsigned short* __restrict__ qk,
                        const float* __restrict__ att0,
                        const float* __restrict__ alphas,
                        unsigned short* __restrict__ att) {
    int b = blockIdx.x;
    int n = b / (3*Tt); int rem = b - n*(3*Tt); int s = rem / Tt; int t = rem - s*Tt;
    __shared__ float qs[32*Vv], ks[32*Vv];
    const unsigned short* qp = qk + (size_t)n*614400 + (size_t)(s*32)*3200 + t*25;
    const unsigned short* kp = qk + (size_t)n*614400 + (size_t)(96 + s*32)*3200 + t*25;
    for (int i = threadIdx.x; i < 32*Vv; i += 256) {
        int c = i / Vv, v = i - c*Vv;
        qs[i] = bf2f(qp[(size_t)c*3200 + v]);
        ks[i] = bf2f(kp[(size_t)c*3200 + v]);
    }
    __syncthreads();
    float alpha = alphas[s];
    for (int i = threadIdx.x; i < Vv*Vv; i += 256) {
        int u = i / Vv, v = i - u*Vv;
        float a = 0.f;
        #pragma unroll
        for (int c = 0; c < 32; ++c) a += qs[c*Vv + u] * ks[c*Vv + v];
        att[(size_t)n*240000 + (size_t)s*80000 + (size_t)t*625 + i] =
            f2bf(att0[s*625 + i] + tanhf(a * (1.f/32.f)) * alpha);
    }
}

// =====================================================================
// MFMA spatial einsum: y2[(s*128+c)][(t0+tl)*25+v] = sum_u x[c][(t0+tl)*25+u]
//                      * att[s][t0+tl][u][v]
// One block per (n, 4 consecutive t). Block-diagonal B over the 4 t's:
// K = 4*32 (u padded 25->32), N = 4*25=100 (padded to 112 = 7 n-tiles).
// A staged bf16 in LDS with ((c&7)<<4) XOR swizzle. att scattered straight
// into MFMA B-fragment layout; Bf zeroed ONCE.
// =====================================================================
__global__ __launch_bounds__(256, 2) void k_eins_mfma(
    const float* __restrict__ X, const unsigned short* __restrict__ att,
    unsigned short* __restrict__ y2)
{
    __shared__ short Xf[128*128];     // [c][tl*32+u] bf16, swizzled (32KB)
    __shared__ short Bf[7*4*64*8];    // frag [nt][ks][lane][j] (28KB)

    const int n  = blockIdx.x >> 5;
    const int t0 = (blockIdx.x & 31) * 4;
    const int tid = threadIdx.x;
    const int wav = tid >> 6, lane = tid & 63;
    const int lq = lane >> 4, l16 = lane & 15;

    for (int i = tid; i < 7*4*64; i += 256)
        *(bf16x8*)(Bf + (size_t)i*8) = (bf16x8){0,0,0,0,0,0,0,0};

    const float* xp = X + (size_t)n*409600;
    for (int i = tid; i < 8192; i += 256) {
        int u2 = (i & 15)*2, tl = (i >> 4) & 3, c = i >> 6;
        float f0 = 0.f, f1 = 0.f;
        if (u2 < 25) {
            const float* p = xp + (size_t)c*3200 + (t0 + tl)*25 + u2;
            f0 = p[0];
            if (u2 < 24) f1 = p[1];
        }
        unsigned pk = (unsigned)f2bf(f0) | ((unsigned)f2bf(f1) << 16);
        int byte = (i*4) ^ ((c & 7) << 4);
        *(unsigned*)((char*)Xf + byte) = pk;
    }
    __syncthreads();

    bf16x8 afr[2][4];
    #pragma unroll
    for (int i = 0; i < 2; ++i) {
        const int c = (2*wav + i)*16 + l16;
        #pragma unroll
        for (int ks = 0; ks < 4; ++ks) {
            int byte = ((c*128 + ks*32 + lq*8)*2) ^ ((c & 7) << 4);
            afr[i][ks] = *(const bf16x8*)((const char*)Xf + byte);
        }
    }

    for (int s = 0; s < 3; ++s) {
        const unsigned short* ap = att + (size_t)n*240000 + (size_t)s*80000
                                       + (size_t)t0*625;
        for (int j = tid; j < 2500; j += 256) {
            int tl = j / 625, r = j - tl*625;
            int u = r / 25, v = r - u*25;
            int col = tl*25 + v;
            int l = ((u >> 3) << 4) | (col & 15);
            int nt = col >> 4;
            Bf[(size_t)((nt*4 + tl)*64 + l)*8 + (u & 7)] = (short)ap[j];
        }
        __syncthreads();

        f32x4 acc[2][7];
        #pragma unroll
        for (int i = 0; i < 2; ++i)
            #pragma unroll
            for (int nt = 0; nt < 7; ++nt) acc[i][nt] = (f32x4){0.f,0.f,0.f,0.f};

        #pragma unroll
        for (int ks = 0; ks < 4; ++ks) {
            bf16x8 bfr[7];
            #pragma unroll
            for (int nt = 0; nt < 7; ++nt)
                bfr[nt] = *(const bf16x8*)(Bf + (size_t)((nt*4 + ks)*64 + lane)*8);
            #pragma unroll
            for (int i = 0; i < 2; ++i)
                #pragma unroll
                for (int nt = 0; nt < 7; ++nt)
                    acc[i][nt] = __builtin_amdgcn_mfma_f32_16x16x32_bf16(
                        afr[i][ks], bfr[nt], acc[i][nt], 0, 0, 0);
        }

        unsigned short* yb = y2 + (size_t)n*1228800 + (size_t)(s*128)*3200 + t0*25;
        #pragma unroll
        for (int i = 0; i < 2; ++i) {
            const int row = (2*wav + i)*16 + lq*4;
            #pragma unroll
            for (int nt = 0; nt < 7; ++nt) {
                const int col = nt*16 + l16;
                if (col < 100) {
                    unsigned short* yp = yb + (size_t)row*3200 + col;
                    #pragma unroll
                    for (int r = 0; r < 4; ++r)
                        yp[(size_t)r*3200] = f2bf(acc[i][nt][r]);
                }
            }
        }
        __syncthreads();
    }
}

// xbar_bf[n*16384 + c*128 + t] = mean_v sout
__global__ void k_mean(const float* __restrict__ X, unsigned short* __restrict__ xb) {
    int idx = blockIdx.x*256 + threadIdx.x;
    if (idx >= Nn*Cc*Tt) return;
    const float* p = X + (size_t)idx*25;
    float s = 0.f;
    #pragma unroll
    for (int v = 0; v < Vv; ++v) s += p[v];
    xb[idx] = f2bf(s * (1.f/25.f));
}

// temporal attention: attb_bf[n][u][(h*128+t)] = mask*alpha*tanh(dot/32)
__global__ void k_att_t(const float* __restrict__ qkt, const float* __restrict__ af,
                        const float* __restrict__ ab, unsigned short* __restrict__ attb) {
    int n = blockIdx.x >> 2, h = blockIdx.x & 3;
    __shared__ float qs[32*Tt], ks[32*Tt];
    const float* qp = qkt + (size_t)n*32768 + (size_t)(h*32)*128;
    const float* kp = qkt + (size_t)n*32768 + (size_t)(128 + h*32)*128;
    for (int i = threadIdx.x; i < 32*Tt; i += 256) { qs[i] = qp[i]; ks[i] = kp[i]; }
    __syncthreads();
    float alpha = (h < 2) ? af[h] : ab[h-2];
    for (int i = threadIdx.x; i < Tt*Tt; i += 256) {
        int u = i >> 7, t = i & 127;
        bool keep = (h < 2) ? (t >= u) : (t <= u);
        float val = 0.f;
        if (keep) {
            float a = 0.f;
            #pragma unroll
            for (int c = 0; c < 32; ++c) a += qs[c*Tt + t] * ks[c*Tt + u];
            val = tanhf(a * (1.f/32.f)) * alpha;
        }
        attb[(size_t)n*65536 + (size_t)u*512 + h*128 + t] = f2bf(val);
    }
}

extern "C" void kernel_launch(void* const* d_in, const int* in_sizes, int n_in,
                              void* d_out, int out_size, void* d_ws, size_t ws_size,
                              hipStream_t stream) {
    const float* x       = (const float*)d_in[0];
    const float* w_in_s  = (const float*)d_in[1];
    const float* b_in_s  = (const float*)d_in[2];
    const float* att0s   = (const float*)d_in[3];
    const float* alphas  = (const float*)d_in[4];
    const float* w_out_s = (const float*)d_in[5];
    const float* b_out_s = (const float*)d_in[6];
    const float* g_out_s = (const float*)d_in[7];
    const float* be_out_s= (const float*)d_in[8];
    const float* w_ff_s  = (const float*)d_in[9];
    const float* b_ff_s  = (const float*)d_in[10];
    const float* g_ff_s  = (const float*)d_in[11];
    const float* be_ff_s = (const float*)d_in[12];
    const float* w_in_t  = (const float*)d_in[13];
    const float* b_in_t  = (const float*)d_in[14];
    const float* alphat_f= (const float*)d_in[15];
    const float* alphat_b= (const float*)d_in[16];
    const float* w_out_t = (const float*)d_in[17];
    const float* b_out_t = (const float*)d_in[18];
    const float* g_out_t = (const float*)d_in[19];
    const float* be_out_t= (const float*)d_in[20];
    const float* w_ff_t  = (const float*)d_in[21];
    const float* b_ff_t  = (const float*)d_in[22];
    const float* g_ff_t  = (const float*)d_in[23];
    const float* be_ff_t = (const float*)d_in[24];
    const float* w_tcn   = (const float*)d_in[25];
    const float* b_tcn   = (const float*)d_in[26];
    const float* g_tcn   = (const float*)d_in[27];
    const float* be_tcn  = (const float*)d_in[28];

    float* ws = (float*)d_ws;
    unsigned short* WB    = (unsigned short*)ws;
    unsigned short* QKBF  = (unsigned short*)(ws + 200000);
    unsigned short* S1BF  = (unsigned short*)(ws + 200000);
    unsigned short* ATSB  = (unsigned short*)(ws + 10030400);
    unsigned short* Y2BF  = (unsigned short*)(ws + 13870400);
    float*          SOUT  = ws + 33531200;
    unsigned short* ATTB  = (unsigned short*)(ws + 200000);
    unsigned short* XBARB = (unsigned short*)(ws + 1300000);
    float*          QKT   = ws + 1600000;
    unsigned short* TMPB  = (unsigned short*)(ws + 2700000);
    unsigned short* T1BF  = (unsigned short*)(ws + 46638400);
    float*          TOUT  = ws + 2700000;
    unsigned short* TOUTB = (unsigned short*)(ws + 15810000);
    float* out = (float*)d_out;

    unsigned short* wbis = WB;
    unsigned short* wbos = WB + 24576;
    unsigned short* wbfs = WB + 73728;
    unsigned short* wbit = WB + 90112;
    unsigned short* wbot = WB + 122880;
    unsigned short* wbft = WB + 188416;
    unsigned short* wbtc = WB + 204800;

    dim3 blk(256);
    const float* NUL = nullptr;

    k_prep<<<1248, blk, 0, stream>>>(w_in_s, w_out_s, w_ff_s, w_in_t,
                                     w_out_t, w_ff_t, w_tcn, WB);

    // ---- spatial ----
    // qk_bf = W_in_s @ x + b      (M=192, K=128, B fp32) : 1600 blocks
    gemm_k<4,0,1><<<1600, blk, 0, stream>>>(
        wbis, x, nullptr, QKBF, NUL, b_in_s, NUL, NUL,
        192, 128, 128, 3200, 3200, 0L, 409600L, 614400L, 25, 50);
    k_att_s<<<Nn*3*Tt, blk, 0, stream>>>(QKBF, att0s, alphas, ATSB);
    k_eins_mfma<<<dim3(Nn*32), blk, 0, stream>>>(x, ATSB, Y2BF);
    // s1_bf = lrelu(x + bn(W_out_s @ y2 + b))   (K=384 fused over heads)
    gemm_k<0,0,1><<<800, blk, 0, stream>>>(
        wbos, Y2BF, nullptr, S1BF, x, b_out_s, g_out_s, be_out_s,
        128, 384, 384, 3200, 3200, 0L, 1228800L, 409600L, 25, 25);
    // sout = lrelu(x + bn(W_ff_s @ s1 + b))
    gemm_k<0,0,0><<<800, blk, 0, stream>>>(
        wbfs, S1BF, SOUT, nullptr, x, b_ff_s, g_ff_s, be_ff_s,
        128, 128, 128, 3200, 3200, 0L, 409600L, 409600L, 25, 25);

    // ---- temporal ----
    k_mean<<<2048, blk, 0, stream>>>(SOUT, XBARB);
    // qkt = W_in_t @ xbar + b     (M=256, K=128, N=128) : 64 blocks
    gemm_k<0,0,0><<<64, blk, 0, stream>>>(
        wbit, XBARB, QKT, nullptr, NUL, b_in_t, NUL, NUL,
        256, 128, 128, 128, 128, 0L, 16384L, 32768L, 1, 2);
    k_att_t<<<Nn*4, blk, 0, stream>>>(QKT, alphat_f, alphat_b, ATTB);
    // tmp_bf[(h,o)] = W_out_t_perm @ sout   (M=512, B fp32) : 3200 blocks
    gemm_k<4,0,1><<<3200, blk, 0, stream>>>(
        wbot, SOUT, nullptr, TMPB, NUL, NUL, NUL, NUL,
        512, 128, 128, 3200, 3200, 0L, 409600L, 1638400L, 25, 100);
    // t1_bf = lrelu(sout + bn(att @ tmp + b))  (K=512 fused over heads, DMODE2)
    gemm_k<3,2,1><<<800, blk, 0, stream>>>(
        ATTB, TMPB, nullptr, T1BF, SOUT, b_out_t, g_out_t, be_out_t,
        128, 512, 512, 3200, 3200, 65536L, 1638400L, 409600L, 25, 25);
    // tout(+bf) = lrelu(sout + bn(W_ff_t @ t1 + b))
    gemm_k<0,0,2><<<800, blk, 0, stream>>>(
        wbft, T1BF, TOUT, TOUTB, SOUT, b_ff_t, g_ff_t, be_ff_t,
        128, 128, 128, 3200, 3200, 0L, 409600L, 409600L, 25, 25);

    // ---- TCN ----
    // out = lrelu(tout + bn(conv7(tout) + b))   (K=896, shifted bf16 B)
    gemm_k<1,0,0><<<800, blk, 0, stream>>>(
        wbtc, TOUTB, out, nullptr, TOUT, b_tcn, g_tcn, be_tcn,
        128, 896, 896, 3200, 3200, 0L, 409600L, 409600L, 25, 25);
}

// Round 11
// 710.014 us; speedup vs baseline: 1.4163x; 1.1398x over previous
//
#include <hip/hip_runtime.h>
#include <cstddef>

#define Nn 32
#define Cc 128
#define Tt 128
#define Vv 25
#define BN_INV 0.9999950000374997f

// ---------------- workspace layout (float offsets), max 53,192,000 ----------
// WB (bf16 weights)    @ 0          (159,744 f as sh)
// QKBF  [n][192][3200] @ 200,000    (9,830,400)   dead after att_s
// S1BF  [n][128][3200] @ 200,000    (reuse, qk dead)
// ATSB  [n][3][t][625] @ 10,030,400 (3,840,000)
// Y2BF  [n][384][3200] @ 13,870,400 (19,660,800)
// SOUT  fp32           @ 33,531,200 (13,107,200)  live til TCN
// ATTB  [n][u][512]    @ 200,000    (reuse, s1 dead)
// XBARB                @ 1,300,000
// QKT   fp32           @ 1,600,000  (1,048,576)
// TMPB  [n][512][3200] @ 2,700,000  (26,214,400)  dead after t1 GEMM
// T1BF  [n][128][3200] @ 46,638,400 (6,553,600)
// TOUT  fp32           @ 2,700,000  (13,107,200, tmp dead)
// TOUTB @ 15,810,000   (6,553,600)
// HISTORY: R4 (BK32/N128/swizzle/reg-staging) = 710us BEST. R3+R10: bigger
// LDS per block regressed (occupancy). R5-R9 gload+layout web: net loss.
// R2: N64 w/o swizzle failed (FETCH doubled, HBM-latency loads). R11 thesis:
// R4's GEMMs are GRID-limited (800 blk = 3.1/CU; barriers idle the CU during
// drains). N64 doubles blocks; WITH the whole-n-per-XCD swizzle the per-n
// B slice stays L2-resident so R2's FETCH penalty is gone. + R2's 1-iter
// register prefetch covers the ~200cyc L2 latency under fragreads+MFMA.

typedef __attribute__((ext_vector_type(8))) short bf16x8;
typedef __attribute__((ext_vector_type(4))) float f32x4;

__device__ __forceinline__ unsigned short f2bf(float f) {
    union { float f; unsigned u; } x; x.f = f;
    return (unsigned short)((x.u + 0x7FFFu + ((x.u >> 16) & 1u)) >> 16);
}
__device__ __forceinline__ float bf2f(unsigned short s) {
    union { unsigned u; float f; } x; x.u = ((unsigned)s) << 16;
    return x.f;
}

// =====================================================================
// MFMA bf16 GEMM, tile 128(M) x 64(N), 256 thr = 4 waves, K-block 32.
// 1D grid, nwg % 8 == 0. XCD swizzle: w = (b&7)*(nwg>>3) + (b>>3);
// n = w/gxn -> whole n's per XCD so per-n B/resp slices stay L2-resident.
// 1-deep register prefetch: GFETCH(k+32) issued after barrier 2, latency
// hides under frag reads + 8 MFMA; wait lands at next iter's LDS write.
// A: bf16 row-major [M][lda] @ A + n*an_stride
// BMODE 0: bf16 row-major [K][ldb]
// BMODE 4: fp32 row-major [K][ldb] (convert in loader)
// BMODE 1: TCN shifted: k=(kidx,c): B[k][col] = Bn[c*3200 + col + (kidx-3)*25]
// BMODE 3: tein: k=(h,t), col=(o,v): B[k][col] = Bn[h*409600 + o*3200 + t*25 + v]
// DMODE 0: addr = m*ldd + col ; DMODE 2: m=u, col=(c,v): addr = c*3200+u*25+v
// OM: 0 fp32 D only, 1 bf16 Dbf only, 2 both
// epilogue: val = acc (+bias); if(gg): val = val*g*BN_INV + bb + resp; lrelu
// =====================================================================

// fetch k-block K0 into (a0n, a1n, bqn[8]); A regs keep old (zero) if mg>=M
#define GFETCH(K0)                                                             \
    {                                                                          \
        int mg = m0 + sm;                                                      \
        if (mg < M) {                                                          \
            const unsigned short* ap = An + (size_t)mg*lda + (K0) + skh*16;    \
            a0n = *(const bf16x8*)ap;                                          \
            a1n = *(const bf16x8*)(ap + 8);                                    \
        }                                                                      \
        if (BMODE == 0) {                                                      \
            const unsigned short* Bn = (const unsigned short*)Bv               \
                                     + (size_t)n*bn_stride;                    \
            _Pragma("unroll")                                                  \
            for (int j = 0; j < 8; ++j)                                        \
                bqn[j] = Bn[(size_t)((K0) + skq*8 + j)*ldb + bcol];            \
        } else if (BMODE == 4) {                                               \
            const float* Bf = (const float*)Bv + (size_t)n*bn_stride;          \
            _Pragma("unroll")                                                  \
            for (int j = 0; j < 8; ++j)                                        \
                bqn[j] = f2bf(Bf[(size_t)((K0) + skq*8 + j)*ldb + bcol]);      \
        } else if (BMODE == 1) {                                               \
            const unsigned short* Bn = (const unsigned short*)Bv               \
                                     + (size_t)n*bn_stride;                    \
            int kb = (K0) + skq*8;                                             \
            int kidx = kb >> 7, c0 = kb & 127;                                 \
            int e = bcol + (kidx - 3)*25;                                      \
            bool ok = ((unsigned)e < 3200u);                                   \
            _Pragma("unroll")                                                  \
            for (int j = 0; j < 8; ++j)                                        \
                bqn[j] = ok ? Bn[(size_t)(c0 + j)*3200 + e] : (unsigned short)0;\
        } else { /* BMODE 3 */                                                 \
            const unsigned short* Bn = (const unsigned short*)Bv               \
                                     + (size_t)n*bn_stride;                    \
            int kb = (K0) + skq*8;                                             \
            int h = kb >> 7, t0b = kb & 127;                                   \
            const unsigned short* bp = Bn + (size_t)h*409600 + (size_t)bo*3200 \
                                          + (size_t)t0b*25 + bv_;              \
            _Pragma("unroll")                                                  \
            for (int j = 0; j < 8; ++j) bqn[j] = bp[j*25];                     \
        }                                                                      \
    }

template<int BMODE, int DMODE, int OM>
__global__ __launch_bounds__(256, 4) void gemm_k(
    const unsigned short* __restrict__ A, const void* __restrict__ Bv,
    float* __restrict__ D, unsigned short* __restrict__ Dbf,
    const float* __restrict__ resp, const float* __restrict__ bias,
    const float* __restrict__ gg, const float* __restrict__ bb,
    int M, int K, int lda, int ldb, int ldd,
    long an_stride, long bn_stride, long dn_stride, int gn, int gxn)
{
    __shared__ short Al[8*64*8];   // 8 m-frags x 64 lane-slots x 8 bf16 (8KB)
    __shared__ short Bl[4*64*8];   // 4 col-frags x 64 lane-slots x 8 bf16 (4KB)

    // ---- XCD-aware bijective swizzle (nwg % 8 == 0 guaranteed) ----
    const int nwg = gridDim.x;
    const int b   = blockIdx.x;
    const int w   = (b & 7)*(nwg >> 3) + (b >> 3);
    const int n   = w / gxn;
    const int rem = w - n*gxn;
    const int mt  = rem / gn;
    const int nt  = rem - mt*gn;
    const int m0 = mt*128;
    const int j0 = nt*64;

    const unsigned short* An = A + (size_t)n*an_stride;

    const int tid = threadIdx.x;
    const int wav = tid >> 6, lane = tid & 63;
    const int lq = lane >> 4, l16 = lane & 15;

    const int sm  = tid >> 1, skh = tid & 1;      // A staging: row, k-half
    const int scol = tid & 63, skq = tid >> 6;    // B staging: col, k-octet
    const int bcol = j0 + scol;

    int bo = 0, bv_ = 0;
    if (BMODE == 3) { bo = bcol/25; bv_ = bcol - 25*bo; }

    f32x4 acc[2][4];
    #pragma unroll
    for (int i = 0; i < 2; ++i)
        #pragma unroll
        for (int c = 0; c < 4; ++c) acc[i][c] = (f32x4){0.f,0.f,0.f,0.f};

    bf16x8 a0n = (bf16x8){0,0,0,0,0,0,0,0}, a1n = a0n;
    unsigned short bqn[8];
    GFETCH(0);

    for (int k0 = 0; k0 < K; k0 += 32) {
        __syncthreads();   // previous tile fully consumed
        {
            short* Ap = Al + ((size_t)((sm>>4)*64 + (sm&15) + 32*skh))*8;
            *(bf16x8*)Ap = a0n;
            *(bf16x8*)(Ap + 128) = a1n;       // +16 lane-slots
        }
        {
            short* Bp = Bl + ((size_t)((scol>>4)*64 + skq*16 + (scol&15)))*8;
            bf16x8 p0;
            #pragma unroll
            for (int j = 0; j < 8; ++j) p0[j] = (short)bqn[j];
            *(bf16x8*)Bp = p0;
        }
        __syncthreads();

        if (k0 + 32 < K) GFETCH(k0 + 32);   // overlap with frag reads + MFMA

        bf16x8 afr[2], bfr[4];
        afr[0] = *(const bf16x8*)(Al + ((size_t)((2*wav+0)*64 + lane))*8);
        afr[1] = *(const bf16x8*)(Al + ((size_t)((2*wav+1)*64 + lane))*8);
        #pragma unroll
        for (int c = 0; c < 4; ++c)
            bfr[c] = *(const bf16x8*)(Bl + ((size_t)(c*64 + lane))*8);
        #pragma unroll
        for (int i = 0; i < 2; ++i)
            #pragma unroll
            for (int c = 0; c < 4; ++c)
                acc[i][c] = __builtin_amdgcn_mfma_f32_16x16x32_bf16(
                    afr[i], bfr[c], acc[i][c], 0, 0, 0);
    }

    // ---- epilogue: row = m0+(2w+i)*16+lq*4+r ; col = j0+ct*16+l16 ----
    #pragma unroll
    for (int i = 0; i < 2; ++i) {
        const int mbase = m0 + (2*wav + i)*16 + lq*4;
        #pragma unroll
        for (int ct = 0; ct < 4; ++ct) {
            const int col = j0 + ct*16 + l16;
            if (DMODE == 0) {
                #pragma unroll
                for (int r = 0; r < 4; ++r) {
                    const int mg = mbase + r;
                    if (mg < M) {
                        const size_t addr = (size_t)mg*ldd + col + (size_t)n*dn_stride;
                        float val = acc[i][ct][r] + (bias ? bias[mg] : 0.f);
                        if (gg) {
                            val = val*(gg[mg]*BN_INV) + bb[mg] + resp[addr];
                            val = val > 0.f ? val : 0.1f*val;
                        }
                        if (OM != 1) D[addr] = val;
                        if (OM >= 1) Dbf[addr] = f2bf(val);
                    }
                }
            } else { // DMODE 2
                const int c = col/25, v = col - 25*c;
                const float bi = bias ? bias[c] : 0.f;
                float gv = 0.f, b2 = 0.f;
                if (gg) { gv = gg[c]*BN_INV; b2 = bb[c]; }
                #pragma unroll
                for (int r = 0; r < 4; ++r) {
                    const int u = mbase + r;
                    const size_t addr = (size_t)c*3200 + (size_t)u*25 + v
                                      + (size_t)n*dn_stride;
                    float val = acc[i][ct][r] + bi;
                    if (gg) {
                        val = val*gv + b2 + resp[addr];
                        val = val > 0.f ? val : 0.1f*val;
                    }
                    if (OM != 1) D[addr] = val;
                    if (OM >= 1) Dbf[addr] = f2bf(val);
                }
            }
        }
    }
}

// weight prep: convert (and permute) all weights to bf16 in WB
__global__ void k_prep(const float* __restrict__ wis, const float* __restrict__ wos,
                       const float* __restrict__ wfs, const float* __restrict__ wit,
                       const float* __restrict__ wot, const float* __restrict__ wft,
                       const float* __restrict__ wtc, unsigned short* __restrict__ W) {
    int i = blockIdx.x*256 + threadIdx.x;
    if (i < 24576) { W[i] = f2bf(wis[i]); return; }          i -= 24576;
    if (i < 49152) { W[24576 + i] = f2bf(wos[i]); return; }  i -= 49152;
    if (i < 16384) { W[73728 + i] = f2bf(wfs[i]); return; }  i -= 16384;
    if (i < 32768) { W[90112 + i] = f2bf(wit[i]); return; }  i -= 32768;
    if (i < 65536) { // [(h*128+o)][c] <- wot[o][h*128+c]
        int ho = i >> 7, c = i & 127; int h = ho >> 7, o = ho & 127;
        W[122880 + i] = f2bf(wot[o*512 + h*128 + c]); return; } i -= 65536;
    if (i < 16384) { W[188416 + i] = f2bf(wft[i]); return; } i -= 16384;
    if (i < 114688) { // [o][kidx*128+c] <- wtc[(o*128+c)*7 + kidx]
        int o = i / 896; int r = i - o*896; int kidx = r >> 7, c = r & 127;
        W[204800 + i] = f2bf(wtc[(o*128 + c)*7 + kidx]); }
}

// spatial attention: atts_bf = att0 + tanh(q.k/32)*alpha  (reads bf16 qk)
__global__ void k_att_s(const unsigned short* __restrict__ qk,
                        const float* __restrict__ att0,
                        const float* __restrict__ alphas,
                        unsigned short* __restrict__ att) {
    int b = blockIdx.x;
    int n = b / (3*Tt); int rem = b - n*(3*Tt); int s = rem / Tt; int t = rem - s*Tt;
    __shared__ float qs[32*Vv], ks[32*Vv];
    const unsigned short* qp = qk + (size_t)n*614400 + (size_t)(s*32)*3200 + t*25;
    const unsigned short* kp = qk + (size_t)n*614400 + (size_t)(96 + s*32)*3200 + t*25;
    for (int i = threadIdx.x; i < 32*Vv; i += 256) {
        int c = i / Vv, v = i - c*Vv;
        qs[i] = bf2f(qp[(size_t)c*3200 + v]);
        ks[i] = bf2f(kp[(size_t)c*3200 + v]);
    }
    __syncthreads();
    float alpha = alphas[s];
    for (int i = threadIdx.x; i < Vv*Vv; i += 256) {
        int u = i / Vv, v = i - u*Vv;
        float a = 0.f;
        #pragma unroll
        for (int c = 0; c < 32; ++c) a += qs[c*Vv + u] * ks[c*Vv + v];
        att[(size_t)n*240000 + (size_t)s*80000 + (size_t)t*625 + i] =
            f2bf(att0[s*625 + i] + tanhf(a * (1.f/32.f)) * alpha);
    }
}

// =====================================================================
// MFMA spatial einsum: y2[(s*128+c)][(t0+tl)*25+v] = sum_u x[c][(t0+tl)*25+u]
//                      * att[s][t0+tl][u][v]
// One block per (n, 4 consecutive t). Block-diagonal B over the 4 t's:
// K = 4*32 (u padded 25->32), N = 4*25=100 (padded to 112 = 7 n-tiles).
// A staged bf16 in LDS with ((c&7)<<4) XOR swizzle. att scattered straight
// into MFMA B-fragment layout; Bf zeroed ONCE.
// =====================================================================
__global__ __launch_bounds__(256, 2) void k_eins_mfma(
    const float* __restrict__ X, const unsigned short* __restrict__ att,
    unsigned short* __restrict__ y2)
{
    __shared__ short Xf[128*128];     // [c][tl*32+u] bf16, swizzled (32KB)
    __shared__ short Bf[7*4*64*8];    // frag [nt][ks][lane][j] (28KB)

    const int n  = blockIdx.x >> 5;
    const int t0 = (blockIdx.x & 31) * 4;
    const int tid = threadIdx.x;
    const int wav = tid >> 6, lane = tid & 63;
    const int lq = lane >> 4, l16 = lane & 15;

    for (int i = tid; i < 7*4*64; i += 256)
        *(bf16x8*)(Bf + (size_t)i*8) = (bf16x8){0,0,0,0,0,0,0,0};

    const float* xp = X + (size_t)n*409600;
    for (int i = tid; i < 8192; i += 256) {
        int u2 = (i & 15)*2, tl = (i >> 4) & 3, c = i >> 6;
        float f0 = 0.f, f1 = 0.f;
        if (u2 < 25) {
            const float* p = xp + (size_t)c*3200 + (t0 + tl)*25 + u2;
            f0 = p[0];
            if (u2 < 24) f1 = p[1];
        }
        unsigned pk = (unsigned)f2bf(f0) | ((unsigned)f2bf(f1) << 16);
        int byte = (i*4) ^ ((c & 7) << 4);
        *(unsigned*)((char*)Xf + byte) = pk;
    }
    __syncthreads();

    bf16x8 afr[2][4];
    #pragma unroll
    for (int i = 0; i < 2; ++i) {
        const int c = (2*wav + i)*16 + l16;
        #pragma unroll
        for (int ks = 0; ks < 4; ++ks) {
            int byte = ((c*128 + ks*32 + lq*8)*2) ^ ((c & 7) << 4);
            afr[i][ks] = *(const bf16x8*)((const char*)Xf + byte);
        }
    }

    for (int s = 0; s < 3; ++s) {
        const unsigned short* ap = att + (size_t)n*240000 + (size_t)s*80000
                                       + (size_t)t0*625;
        for (int j = tid; j < 2500; j += 256) {
            int tl = j / 625, r = j - tl*625;
            int u = r / 25, v = r - u*25;
            int col = tl*25 + v;
            int l = ((u >> 3) << 4) | (col & 15);
            int nt = col >> 4;
            Bf[(size_t)((nt*4 + tl)*64 + l)*8 + (u & 7)] = (short)ap[j];
        }
        __syncthreads();

        f32x4 acc[2][7];
        #pragma unroll
        for (int i = 0; i < 2; ++i)
            #pragma unroll
            for (int nt = 0; nt < 7; ++nt) acc[i][nt] = (f32x4){0.f,0.f,0.f,0.f};

        #pragma unroll
        for (int ks = 0; ks < 4; ++ks) {
            bf16x8 bfr[7];
            #pragma unroll
            for (int nt = 0; nt < 7; ++nt)
                bfr[nt] = *(const bf16x8*)(Bf + (size_t)((nt*4 + ks)*64 + lane)*8);
            #pragma unroll
            for (int i = 0; i < 2; ++i)
                #pragma unroll
                for (int nt = 0; nt < 7; ++nt)
                    acc[i][nt] = __builtin_amdgcn_mfma_f32_16x16x32_bf16(
                        afr[i][ks], bfr[nt], acc[i][nt], 0, 0, 0);
        }

        unsigned short* yb = y2 + (size_t)n*1228800 + (size_t)(s*128)*3200 + t0*25;
        #pragma unroll
        for (int i = 0; i < 2; ++i) {
            const int row = (2*wav + i)*16 + lq*4;
            #pragma unroll
            for (int nt = 0; nt < 7; ++nt) {
                const int col = nt*16 + l16;
                if (col < 100) {
                    unsigned short* yp = yb + (size_t)row*3200 + col;
                    #pragma unroll
                    for (int r = 0; r < 4; ++r)
                        yp[(size_t)r*3200] = f2bf(acc[i][nt][r]);
                }
            }
        }
        __syncthreads();
    }
}

// xbar_bf[n*16384 + c*128 + t] = mean_v sout
__global__ void k_mean(const float* __restrict__ X, unsigned short* __restrict__ xb) {
    int idx = blockIdx.x*256 + threadIdx.x;
    if (idx >= Nn*Cc*Tt) return;
    const float* p = X + (size_t)idx*25;
    float s = 0.f;
    #pragma unroll
    for (int v = 0; v < Vv; ++v) s += p[v];
    xb[idx] = f2bf(s * (1.f/25.f));
}

// temporal attention: attb_bf[n][u][(h*128+t)] = mask*alpha*tanh(dot/32)
__global__ void k_att_t(const float* __restrict__ qkt, const float* __restrict__ af,
                        const float* __restrict__ ab, unsigned short* __restrict__ attb) {
    int n = blockIdx.x >> 2, h = blockIdx.x & 3;
    __shared__ float qs[32*Tt], ks[32*Tt];
    const float* qp = qkt + (size_t)n*32768 + (size_t)(h*32)*128;
    const float* kp = qkt + (size_t)n*32768 + (size_t)(128 + h*32)*128;
    for (int i = threadIdx.x; i < 32*Tt; i += 256) { qs[i] = qp[i]; ks[i] = kp[i]; }
    __syncthreads();
    float alpha = (h < 2) ? af[h] : ab[h-2];
    for (int i = threadIdx.x; i < Tt*Tt; i += 256) {
        int u = i >> 7, t = i & 127;
        bool keep = (h < 2) ? (t >= u) : (t <= u);
        float val = 0.f;
        if (keep) {
            float a = 0.f;
            #pragma unroll
            for (int c = 0; c < 32; ++c) a += qs[c*Tt + t] * ks[c*Tt + u];
            val = tanhf(a * (1.f/32.f)) * alpha;
        }
        attb[(size_t)n*65536 + (size_t)u*512 + h*128 + t] = f2bf(val);
    }
}

extern "C" void kernel_launch(void* const* d_in, const int* in_sizes, int n_in,
                              void* d_out, int out_size, void* d_ws, size_t ws_size,
                              hipStream_t stream) {
    const float* x       = (const float*)d_in[0];
    const float* w_in_s  = (const float*)d_in[1];
    const float* b_in_s  = (const float*)d_in[2];
    const float* att0s   = (const float*)d_in[3];
    const float* alphas  = (const float*)d_in[4];
    const float* w_out_s = (const float*)d_in[5];
    const float* b_out_s = (const float*)d_in[6];
    const float* g_out_s = (const float*)d_in[7];
    const float* be_out_s= (const float*)d_in[8];
    const float* w_ff_s  = (const float*)d_in[9];
    const float* b_ff_s  = (const float*)d_in[10];
    const float* g_ff_s  = (const float*)d_in[11];
    const float* be_ff_s = (const float*)d_in[12];
    const float* w_in_t  = (const float*)d_in[13];
    const float* b_in_t  = (const float*)d_in[14];
    const float* alphat_f= (const float*)d_in[15];
    const float* alphat_b= (const float*)d_in[16];
    const float* w_out_t = (const float*)d_in[17];
    const float* b_out_t = (const float*)d_in[18];
    const float* g_out_t = (const float*)d_in[19];
    const float* be_out_t= (const float*)d_in[20];
    const float* w_ff_t  = (const float*)d_in[21];
    const float* b_ff_t  = (const float*)d_in[22];
    const float* g_ff_t  = (const float*)d_in[23];
    const float* be_ff_t = (const float*)d_in[24];
    const float* w_tcn   = (const float*)d_in[25];
    const float* b_tcn   = (const float*)d_in[26];
    const float* g_tcn   = (const float*)d_in[27];
    const float* be_tcn  = (const float*)d_in[28];

    float* ws = (float*)d_ws;
    unsigned short* WB    = (unsigned short*)ws;
    unsigned short* QKBF  = (unsigned short*)(ws + 200000);
    unsigned short* S1BF  = (unsigned short*)(ws + 200000);
    unsigned short* ATSB  = (unsigned short*)(ws + 10030400);
    unsigned short* Y2BF  = (unsigned short*)(ws + 13870400);
    float*          SOUT  = ws + 33531200;
    unsigned short* ATTB  = (unsigned short*)(ws + 200000);
    unsigned short* XBARB = (unsigned short*)(ws + 1300000);
    float*          QKT   = ws + 1600000;
    unsigned short* TMPB  = (unsigned short*)(ws + 2700000);
    unsigned short* T1BF  = (unsigned short*)(ws + 46638400);
    float*          TOUT  = ws + 2700000;
    unsigned short* TOUTB = (unsigned short*)(ws + 15810000);
    float* out = (float*)d_out;

    unsigned short* wbis = WB;
    unsigned short* wbos = WB + 24576;
    unsigned short* wbfs = WB + 73728;
    unsigned short* wbit = WB + 90112;
    unsigned short* wbot = WB + 122880;
    unsigned short* wbft = WB + 188416;
    unsigned short* wbtc = WB + 204800;

    dim3 blk(256);
    const float* NUL = nullptr;

    k_prep<<<1248, blk, 0, stream>>>(w_in_s, w_out_s, w_ff_s, w_in_t,
                                     w_out_t, w_ff_t, w_tcn, WB);

    // ---- spatial ----
    // qk_bf = W_in_s @ x + b  (M=192: 2 m-tiles x 50 n-tiles) : 3200 blocks
    gemm_k<4,0,1><<<3200, blk, 0, stream>>>(
        wbis, x, nullptr, QKBF, NUL, b_in_s, NUL, NUL,
        192, 128, 128, 3200, 3200, 0L, 409600L, 614400L, 50, 100);
    k_att_s<<<Nn*3*Tt, blk, 0, stream>>>(QKBF, att0s, alphas, ATSB);
    k_eins_mfma<<<dim3(Nn*32), blk, 0, stream>>>(x, ATSB, Y2BF);
    // s1_bf = lrelu(x + bn(W_out_s @ y2 + b))   (K=384) : 1600 blocks
    gemm_k<0,0,1><<<1600, blk, 0, stream>>>(
        wbos, Y2BF, nullptr, S1BF, x, b_out_s, g_out_s, be_out_s,
        128, 384, 384, 3200, 3200, 0L, 1228800L, 409600L, 50, 50);
    // sout = lrelu(x + bn(W_ff_s @ s1 + b)) : 1600 blocks
    gemm_k<0,0,0><<<1600, blk, 0, stream>>>(
        wbfs, S1BF, SOUT, nullptr, x, b_ff_s, g_ff_s, be_ff_s,
        128, 128, 128, 3200, 3200, 0L, 409600L, 409600L, 50, 50);

    // ---- temporal ----
    k_mean<<<2048, blk, 0, stream>>>(SOUT, XBARB);
    // qkt = W_in_t @ xbar + b  (M=256: 2 m x 2 n) : 128 blocks
    gemm_k<0,0,0><<<128, blk, 0, stream>>>(
        wbit, XBARB, QKT, nullptr, NUL, b_in_t, NUL, NUL,
        256, 128, 128, 128, 128, 0L, 16384L, 32768L, 2, 4);
    k_att_t<<<Nn*4, blk, 0, stream>>>(QKT, alphat_f, alphat_b, ATTB);
    // tmp_bf[(h,o)] = W_out_t_perm @ sout  (M=512: 4 m x 50 n) : 6400 blocks
    gemm_k<4,0,1><<<6400, blk, 0, stream>>>(
        wbot, SOUT, nullptr, TMPB, NUL, NUL, NUL, NUL,
        512, 128, 128, 3200, 3200, 0L, 409600L, 1638400L, 50, 200);
    // t1_bf = lrelu(sout + bn(att @ tmp + b))  (K=512, DMODE2) : 1600 blocks
    gemm_k<3,2,1><<<1600, blk, 0, stream>>>(
        ATTB, TMPB, nullptr, T1BF, SOUT, b_out_t, g_out_t, be_out_t,
        128, 512, 512, 3200, 3200, 65536L, 1638400L, 409600L, 50, 50);
    // tout(+bf) = lrelu(sout + bn(W_ff_t @ t1 + b)) : 1600 blocks
    gemm_k<0,0,2><<<1600, blk, 0, stream>>>(
        wbft, T1BF, TOUT, TOUTB, SOUT, b_ff_t, g_ff_t, be_ff_t,
        128, 128, 128, 3200, 3200, 0L, 409600L, 409600L, 50, 50);

    // ---- TCN ----
    // out = lrelu(tout + bn(conv7(tout) + b))  (K=896, BMODE1) : 1600 blocks
    gemm_k<1,0,0><<<1600, blk, 0, stream>>>(
        wbtc, TOUTB, out, nullptr, TOUT, b_tcn, g_tcn, be_tcn,
        128, 896, 896, 3200, 3200, 0L, 409600L, 409600L, 50, 50);
}

// Round 12
// 706.301 us; speedup vs baseline: 1.4237x; 1.0053x over previous
//
#include <hip/hip_runtime.h>
#include <cstddef>

#define Nn 32
#define Cc 128
#define Tt 128
#define Vv 25
#define BN_INV 0.9999950000374997f

// ---------------- workspace layout (float offsets), max 53,192,000 ----------
// WB (bf16 weights)    @ 0
// QKBF  [n][192][3200] @ 200,000    row-major (att_s reads it)
// S1BF_T [n][3200][128]@ 200,000    (reuse, qk dead) k-contig (s1 flush)
// ATSB  [n][3][t][625] @ 10,030,400
// Y2BF_T [n][3200][384]@ 13,870,400 k-contig (k_eins writes transposed)
// TOUTB_T padded       @ 23,710,000 (13,721,600 sh: 32n x [9600|409600|9600])
// SOUT  fp32           @ 33,531,200 row-major
// ATTB  [n][u][512]    @ 200,000    (reuse after ff_s consumed S1T)
// XBARB_T [n][t][c]    @ 1,300,000  k-contig
// QKT   fp32           @ 1,600,000
// TMPB  [n][512][3200] @ 2,700,000  ROW-MAJOR (R4 mode; v-major was R9 regress)
// T1BF  [n][128][3200] @ 46,638,400 row-major (R4 DMODE2)
// TOUT  fp32           @ 2,700,000  (reuse, TMPB dead)
// !! TOUTBP overlaps Y2T and TMPB ranges -> k_zpad AFTER t1 (R5/R6 lesson).
// HISTORY: R4/R11 = 710us best; 6 levers (occ/FETCH/conflicts/gload/BK64/
// prefetch) all moved counters but not duration. R12: vector k-contig B
// (m92 pattern) ONLY where the writer is coalesced (R9-proven pieces):
// s1/ff_s/qkt/TCN. tmp/t1/qk stay scalar row-major (their transposes were
// the R7/R9 write/read-scatter regressions).

typedef __attribute__((ext_vector_type(8))) short bf16x8;
typedef __attribute__((ext_vector_type(4))) short short4v;
typedef __attribute__((ext_vector_type(4))) float f32x4;

__device__ __forceinline__ unsigned short f2bf(float f) {
    union { float f; unsigned u; } x; x.f = f;
    return (unsigned short)((x.u + 0x7FFFu + ((x.u >> 16) & 1u)) >> 16);
}
__device__ __forceinline__ float bf2f(unsigned short s) {
    union { unsigned u; float f; } x; x.u = ((unsigned)s) << 16;
    return x.f;
}

// =====================================================================
// MFMA bf16 GEMM, tile 128(M) x 64(N), 256 thr = 4 waves, K-block 32.
// 1D grid, nwg % 8 == 0. XCD swizzle: w = (b&7)*(nwg>>3) + (b>>3);
// n = w/gxn -> whole n's per XCD (per-n B/resp slices L2-resident).
// 1-deep register prefetch (GFETCH(k+32) after barrier 2).
// BMODE 0: bf16 row-major [K][ldb], 8 scalar loads
// BMODE 1: TCN shifted row-major (legacy, unused now)
// BMODE 3: tein: k=(h,t), col=(o,v): B = Bn[h*409600+o*3200+t*25+v] scalar
// BMODE 4: fp32 row-major [K][ldb], f2bf in regs
// BMODE 6: bf16 K-CONTIG [col][ldb]: ONE bf16x8 vector load
// BMODE 7: TCN k-contig padded [e][128c]: ONE vector load, e=col+(kidx-3)*25
// DMODE 0: D/Dbf row-major m*ldd+col
// DMODE 1: Dbf transposed [col][128] via LDS flush (M==128); D/resp row-major
// DMODE 2: t1: m=u, col=(c,v): addr = c*3200+u*25+v (row-major T1BF)
// OM: 0 fp32 D only, 1 bf16 Dbf only, 2 both
// =====================================================================

// fetch k-block K0 into (a0n, a1n, bqn[8])
#define GFETCH(K0)                                                             \
    {                                                                          \
        int mg = m0 + sm;                                                      \
        if (mg < M) {                                                          \
            const unsigned short* ap = An + (size_t)mg*lda + (K0) + skh*16;    \
            a0n = *(const bf16x8*)ap;                                          \
            a1n = *(const bf16x8*)(ap + 8);                                    \
        }                                                                      \
        if (BMODE == 0) {                                                      \
            const unsigned short* Bn = (const unsigned short*)Bv               \
                                     + (size_t)n*bn_stride;                    \
            _Pragma("unroll")                                                  \
            for (int j = 0; j < 8; ++j)                                        \
                bqn[j] = Bn[(size_t)((K0) + skq*8 + j)*ldb + bcol];            \
        } else if (BMODE == 4) {                                               \
            const float* Bf = (const float*)Bv + (size_t)n*bn_stride;          \
            _Pragma("unroll")                                                  \
            for (int j = 0; j < 8; ++j)                                        \
                bqn[j] = f2bf(Bf[(size_t)((K0) + skq*8 + j)*ldb + bcol]);      \
        } else if (BMODE == 1) {                                               \
            const unsigned short* Bn = (const unsigned short*)Bv               \
                                     + (size_t)n*bn_stride;                    \
            int kb = (K0) + skq*8;                                             \
            int kidx = kb >> 7, c0 = kb & 127;                                 \
            int e = bcol + (kidx - 3)*25;                                      \
            bool ok = ((unsigned)e < 3200u);                                   \
            _Pragma("unroll")                                                  \
            for (int j = 0; j < 8; ++j)                                        \
                bqn[j] = ok ? Bn[(size_t)(c0 + j)*3200 + e] : (unsigned short)0;\
        } else if (BMODE == 3) {                                               \
            const unsigned short* Bn = (const unsigned short*)Bv               \
                                     + (size_t)n*bn_stride;                    \
            int kb = (K0) + skq*8;                                             \
            int h = kb >> 7, t0b = kb & 127;                                   \
            const unsigned short* bp = Bn + (size_t)h*409600 + (size_t)bo*3200 \
                                          + (size_t)t0b*25 + bv_;              \
            _Pragma("unroll")                                                  \
            for (int j = 0; j < 8; ++j) bqn[j] = bp[j*25];                     \
        } else if (BMODE == 6) {                                               \
            const unsigned short* Bn = (const unsigned short*)Bv               \
                                     + (size_t)n*bn_stride;                    \
            *(bf16x8*)bqn = *(const bf16x8*)(Bn + (size_t)bcol*ldb             \
                                             + (K0) + skq*8);                  \
        } else { /* BMODE 7 */                                                 \
            const unsigned short* Bn = (const unsigned short*)Bv               \
                                     + (size_t)n*bn_stride;                    \
            int kb = (K0) + skq*8;                                             \
            int kidx = kb >> 7, c0 = kb & 127;                                 \
            long e = (long)bcol + (long)(kidx - 3)*25;                         \
            *(bf16x8*)bqn = *(const bf16x8*)(Bn + e*128 + c0);                 \
        }                                                                      \
    }

template<int BMODE, int DMODE, int OM>
__global__ __launch_bounds__(256, 4) void gemm_k(
    const unsigned short* __restrict__ A, const void* __restrict__ Bv,
    float* __restrict__ D, unsigned short* __restrict__ Dbf,
    const float* __restrict__ resp, const float* __restrict__ bias,
    const float* __restrict__ gg, const float* __restrict__ bb,
    int M, int K, int lda, int ldb, int ldd,
    long an_stride, long bn_stride, long dn_stride, long dbfn,
    int gn, int gxn)
{
    __shared__ short Al[8*64*8];   // 8KB
    __shared__ short Bl[4*64*8];   // 4KB
    __shared__ __attribute__((aligned(16))) short Ot[(DMODE==1) ? 64*136 : 4];

    // ---- XCD-aware bijective swizzle (nwg % 8 == 0 guaranteed) ----
    const int nwg = gridDim.x;
    const int b   = blockIdx.x;
    const int w   = (b & 7)*(nwg >> 3) + (b >> 3);
    const int n   = w / gxn;
    const int rem = w - n*gxn;
    const int mt  = rem / gn;
    const int nt  = rem - mt*gn;
    const int m0 = mt*128;
    const int j0 = nt*64;

    const unsigned short* An = A + (size_t)n*an_stride;

    const int tid = threadIdx.x;
    const int wav = tid >> 6, lane = tid & 63;
    const int lq = lane >> 4, l16 = lane & 15;

    const int sm  = tid >> 1, skh = tid & 1;      // A staging: row, k-half
    const int scol = tid & 63, skq = tid >> 6;    // B staging: col, k-octet
    const int bcol = j0 + scol;

    int bo = 0, bv_ = 0;
    if (BMODE == 3) { bo = bcol/25; bv_ = bcol - 25*bo; }

    f32x4 acc[2][4];
    #pragma unroll
    for (int i = 0; i < 2; ++i)
        #pragma unroll
        for (int c = 0; c < 4; ++c) acc[i][c] = (f32x4){0.f,0.f,0.f,0.f};

    bf16x8 a0n = (bf16x8){0,0,0,0,0,0,0,0}, a1n = a0n;
    alignas(16) unsigned short bqn[8];
    GFETCH(0);

    for (int k0 = 0; k0 < K; k0 += 32) {
        __syncthreads();   // previous tile fully consumed
        {
            short* Ap = Al + ((size_t)((sm>>4)*64 + (sm&15) + 32*skh))*8;
            *(bf16x8*)Ap = a0n;
            *(bf16x8*)(Ap + 128) = a1n;       // +16 lane-slots
        }
        {
            short* Bp = Bl + ((size_t)((scol>>4)*64 + skq*16 + (scol&15)))*8;
            *(bf16x8*)Bp = *(const bf16x8*)bqn;
        }
        __syncthreads();

        if (k0 + 32 < K) GFETCH(k0 + 32);   // overlap with frag reads + MFMA

        bf16x8 afr[2], bfr[4];
        afr[0] = *(const bf16x8*)(Al + ((size_t)((2*wav+0)*64 + lane))*8);
        afr[1] = *(const bf16x8*)(Al + ((size_t)((2*wav+1)*64 + lane))*8);
        #pragma unroll
        for (int c = 0; c < 4; ++c)
            bfr[c] = *(const bf16x8*)(Bl + ((size_t)(c*64 + lane))*8);
        #pragma unroll
        for (int i = 0; i < 2; ++i)
            #pragma unroll
            for (int c = 0; c < 4; ++c)
                acc[i][c] = __builtin_amdgcn_mfma_f32_16x16x32_bf16(
                    afr[i], bfr[c], acc[i][c], 0, 0, 0);
    }

    // ---- epilogues ----
    if (DMODE == 1) {
        // LDS-transposed flush (M==128, m0==0): Dbf tile [col][128] coalesced.
        #pragma unroll
        for (int i = 0; i < 2; ++i) {
            const int mbase = (2*wav + i)*16 + lq*4;
            #pragma unroll
            for (int ct = 0; ct < 4; ++ct) {
                const int col = j0 + ct*16 + l16;
                short4v pk;
                #pragma unroll
                for (int r = 0; r < 4; ++r) {
                    const int mg = mbase + r;
                    const size_t addr = (size_t)mg*ldd + col + (size_t)n*dn_stride;
                    float val = acc[i][ct][r] + (bias ? bias[mg] : 0.f);
                    if (gg) {
                        val = val*(gg[mg]*BN_INV) + bb[mg] + resp[addr];
                        val = val > 0.f ? val : 0.1f*val;
                    }
                    if (OM != 1) D[addr] = val;
                    pk[r] = (short)f2bf(val);
                }
                *(short4v*)(Ot + (ct*16 + l16)*136 + mbase) = pk;
            }
        }
        __syncthreads();
        #pragma unroll
        for (int j = 0; j < 4; ++j) {
            int idx = j*256 + tid;                 // 1024 chunks of 8 shorts
            int cl = idx >> 4, m8 = (idx & 15)*8;  // (R9-fixed decode)
            *(bf16x8*)(Dbf + (size_t)(j0 + cl)*128 + m8 + (size_t)n*dbfn)
                = *(const bf16x8*)(Ot + cl*136 + m8);
        }
    } else {
        #pragma unroll
        for (int i = 0; i < 2; ++i) {
            const int mbase = m0 + (2*wav + i)*16 + lq*4;
            #pragma unroll
            for (int ct = 0; ct < 4; ++ct) {
                const int col = j0 + ct*16 + l16;
                if (DMODE == 0) {
                    #pragma unroll
                    for (int r = 0; r < 4; ++r) {
                        const int mg = mbase + r;
                        if (mg < M) {
                            const size_t addr = (size_t)mg*ldd + col
                                              + (size_t)n*dn_stride;
                            float val = acc[i][ct][r] + (bias ? bias[mg] : 0.f);
                            if (gg) {
                                val = val*(gg[mg]*BN_INV) + bb[mg] + resp[addr];
                                val = val > 0.f ? val : 0.1f*val;
                            }
                            if (OM != 1) D[addr] = val;
                            if (OM >= 1) Dbf[addr] = f2bf(val);
                        }
                    }
                } else { // DMODE 2 (t1, row-major T1BF)
                    const int c = col/25, v = col - 25*c;
                    const float bi = bias ? bias[c] : 0.f;
                    float gv = 0.f, b2 = 0.f;
                    if (gg) { gv = gg[c]*BN_INV; b2 = bb[c]; }
                    #pragma unroll
                    for (int r = 0; r < 4; ++r) {
                        const int u = mbase + r;
                        const size_t addr = (size_t)c*3200 + (size_t)u*25 + v
                                          + (size_t)n*dn_stride;
                        float val = acc[i][ct][r] + bi;
                        if (gg) {
                            val = val*gv + b2 + resp[addr];
                            val = val > 0.f ? val : 0.1f*val;
                        }
                        if (OM != 1) D[addr] = val;
                        if (OM >= 1) Dbf[addr] = f2bf(val);
                    }
                }
            }
        }
    }
}

// weight prep: convert (and permute) all weights to bf16 in WB
__global__ void k_prep(const float* __restrict__ wis, const float* __restrict__ wos,
                       const float* __restrict__ wfs, const float* __restrict__ wit,
                       const float* __restrict__ wot, const float* __restrict__ wft,
                       const float* __restrict__ wtc, unsigned short* __restrict__ W) {
    int i = blockIdx.x*256 + threadIdx.x;
    if (i < 24576) { W[i] = f2bf(wis[i]); return; }          i -= 24576;
    if (i < 49152) { W[24576 + i] = f2bf(wos[i]); return; }  i -= 49152;
    if (i < 16384) { W[73728 + i] = f2bf(wfs[i]); return; }  i -= 16384;
    if (i < 32768) { W[90112 + i] = f2bf(wit[i]); return; }  i -= 32768;
    if (i < 65536) { // [(h*128+o)][c] <- wot[o][h*128+c]
        int ho = i >> 7, c = i & 127; int h = ho >> 7, o = ho & 127;
        W[122880 + i] = f2bf(wot[o*512 + h*128 + c]); return; } i -= 65536;
    if (i < 16384) { W[188416 + i] = f2bf(wft[i]); return; } i -= 16384;
    if (i < 114688) { // [o][kidx*128+c] <- wtc[(o*128+c)*7 + kidx]
        int o = i / 896; int r = i - o*896; int kidx = r >> 7, c = r & 127;
        W[204800 + i] = f2bf(wtc[(o*128 + c)*7 + kidx]); }
}

// zero the TCN pad margins: per n, shorts [0,9600) and [419200,428800).
// MUST run after t1 (TOUTBP overlaps Y2T and TMPB; t1 is last TMPB reader).
__global__ void k_zpad(unsigned short* __restrict__ p) {
    int i = blockIdx.x*256 + threadIdx.x;     // 76800 threads x 8 shorts
    if (i >= 76800) return;
    int chunk = i*8;
    int n = chunk / 19200;
    int r = chunk - n*19200;
    size_t addr = (size_t)n*428800 + (size_t)(r < 9600 ? r : 419200 + (r - 9600));
    *(bf16x8*)(p + addr) = (bf16x8){0,0,0,0,0,0,0,0};
}

// spatial attention: atts_bf = att0 + tanh(q.k/32)*alpha  (reads bf16 qk)
__global__ void k_att_s(const unsigned short* __restrict__ qk,
                        const float* __restrict__ att0,
                        const float* __restrict__ alphas,
                        unsigned short* __restrict__ att) {
    int b = blockIdx.x;
    int n = b / (3*Tt); int rem = b - n*(3*Tt); int s = rem / Tt; int t = rem - s*Tt;
    __shared__ float qs[32*Vv], ks[32*Vv];
    const unsigned short* qp = qk + (size_t)n*614400 + (size_t)(s*32)*3200 + t*25;
    const unsigned short* kp = qk + (size_t)n*614400 + (size_t)(96 + s*32)*3200 + t*25;
    for (int i = threadIdx.x; i < 32*Vv; i += 256) {
        int c = i / Vv, v = i - c*Vv;
        qs[i] = bf2f(qp[(size_t)c*3200 + v]);
        ks[i] = bf2f(kp[(size_t)c*3200 + v]);
    }
    __syncthreads();
    float alpha = alphas[s];
    for (int i = threadIdx.x; i < Vv*Vv; i += 256) {
        int u = i / Vv, v = i - u*Vv;
        float a = 0.f;
        #pragma unroll
        for (int c = 0; c < 32; ++c) a += qs[c*Vv + u] * ks[c*Vv + v];
        att[(size_t)n*240000 + (size_t)s*80000 + (size_t)t*625 + i] =
            f2bf(att0[s*625 + i] + tanhf(a * (1.f/32.f)) * alpha);
    }
}

// =====================================================================
// MFMA spatial einsum -> Y2 TRANSPOSED: y2T[(t*25+v)*384 + s*128 + c]
// (k-contiguous for s1's BMODE6 vector fetch; R9-proven writer)
// =====================================================================
__global__ __launch_bounds__(256, 2) void k_eins_mfma(
    const float* __restrict__ X, const unsigned short* __restrict__ att,
    unsigned short* __restrict__ y2)
{
    __shared__ short Xf[128*128];     // [c][tl*32+u] bf16, swizzled (32KB)
    __shared__ short Bf[7*4*64*8];    // frag [nt][ks][lane][j] (28KB)

    const int n  = blockIdx.x >> 5;
    const int t0 = (blockIdx.x & 31) * 4;
    const int tid = threadIdx.x;
    const int wav = tid >> 6, lane = tid & 63;
    const int lq = lane >> 4, l16 = lane & 15;

    for (int i = tid; i < 7*4*64; i += 256)
        *(bf16x8*)(Bf + (size_t)i*8) = (bf16x8){0,0,0,0,0,0,0,0};

    const float* xp = X + (size_t)n*409600;
    for (int i = tid; i < 8192; i += 256) {
        int u2 = (i & 15)*2, tl = (i >> 4) & 3, c = i >> 6;
        float f0 = 0.f, f1 = 0.f;
        if (u2 < 25) {
            const float* p = xp + (size_t)c*3200 + (t0 + tl)*25 + u2;
            f0 = p[0];
            if (u2 < 24) f1 = p[1];
        }
        unsigned pk = (unsigned)f2bf(f0) | ((unsigned)f2bf(f1) << 16);
        int byte = (i*4) ^ ((c & 7) << 4);
        *(unsigned*)((char*)Xf + byte) = pk;
    }
    __syncthreads();

    bf16x8 afr[2][4];
    #pragma unroll
    for (int i = 0; i < 2; ++i) {
        const int c = (2*wav + i)*16 + l16;
        #pragma unroll
        for (int ks = 0; ks < 4; ++ks) {
            int byte = ((c*128 + ks*32 + lq*8)*2) ^ ((c & 7) << 4);
            afr[i][ks] = *(const bf16x8*)((const char*)Xf + byte);
        }
    }

    for (int s = 0; s < 3; ++s) {
        const unsigned short* ap = att + (size_t)n*240000 + (size_t)s*80000
                                       + (size_t)t0*625;
        for (int j = tid; j < 2500; j += 256) {
            int tl = j / 625, r = j - tl*625;
            int u = r / 25, v = r - u*25;
            int col = tl*25 + v;
            int l = ((u >> 3) << 4) | (col & 15);
            int nt = col >> 4;
            Bf[(size_t)((nt*4 + tl)*64 + l)*8 + (u & 7)] = (short)ap[j];
        }
        __syncthreads();

        f32x4 acc[2][7];
        #pragma unroll
        for (int i = 0; i < 2; ++i)
            #pragma unroll
            for (int nt = 0; nt < 7; ++nt) acc[i][nt] = (f32x4){0.f,0.f,0.f,0.f};

        #pragma unroll
        for (int ks = 0; ks < 4; ++ks) {
            bf16x8 bfr[7];
            #pragma unroll
            for (int nt = 0; nt < 7; ++nt)
                bfr[nt] = *(const bf16x8*)(Bf + (size_t)((nt*4 + ks)*64 + lane)*8);
            #pragma unroll
            for (int i = 0; i < 2; ++i)
                #pragma unroll
                for (int nt = 0; nt < 7; ++nt)
                    acc[i][nt] = __builtin_amdgcn_mfma_f32_16x16x32_bf16(
                        afr[i][ks], bfr[nt], acc[i][nt], 0, 0, 0);
        }

        // transposed write: y2T[(t0*25+col)*384 + s*128 + row..row+3]
        unsigned short* yb = y2 + (size_t)n*1228800;
        #pragma unroll
        for (int i = 0; i < 2; ++i) {
            const int row = (2*wav + i)*16 + lq*4;
            #pragma unroll
            for (int nt = 0; nt < 7; ++nt) {
                const int col = nt*16 + l16;
                if (col < 100) {
                    short4v pk;
                    #pragma unroll
                    for (int r = 0; r < 4; ++r) pk[r] = (short)f2bf(acc[i][nt][r]);
                    *(short4v*)(yb + (size_t)(t0*25 + col)*384 + s*128 + row) = pk;
                }
            }
        }
        __syncthreads();
    }
}

// xbarT[n][t*128 + c] = mean_v sout  (k-contiguous for qkt BMODE6)
__global__ void k_mean(const float* __restrict__ X, unsigned short* __restrict__ xb) {
    int idx = blockIdx.x*256 + threadIdx.x;
    if (idx >= Nn*Cc*Tt) return;
    const float* p = X + (size_t)idx*25;
    float s = 0.f;
    #pragma unroll
    for (int v = 0; v < Vv; ++v) s += p[v];
    int n = idx >> 14, rem = idx & 16383, c = rem >> 7, t = rem & 127;
    xb[(size_t)n*16384 + (size_t)t*128 + c] = f2bf(s * (1.f/25.f));
}

// temporal attention: attb_bf[n][u][(h*128+t)] = mask*alpha*tanh(dot/32)
__global__ void k_att_t(const float* __restrict__ qkt, const float* __restrict__ af,
                        const float* __restrict__ ab, unsigned short* __restrict__ attb) {
    int n = blockIdx.x >> 2, h = blockIdx.x & 3;
    __shared__ float qs[32*Tt], ks[32*Tt];
    const float* qp = qkt + (size_t)n*32768 + (size_t)(h*32)*128;
    const float* kp = qkt + (size_t)n*32768 + (size_t)(128 + h*32)*128;
    for (int i = threadIdx.x; i < 32*Tt; i += 256) { qs[i] = qp[i]; ks[i] = kp[i]; }
    __syncthreads();
    float alpha = (h < 2) ? af[h] : ab[h-2];
    for (int i = threadIdx.x; i < Tt*Tt; i += 256) {
        int u = i >> 7, t = i & 127;
        bool keep = (h < 2) ? (t >= u) : (t <= u);
        float val = 0.f;
        if (keep) {
            float a = 0.f;
            #pragma unroll
            for (int c = 0; c < 32; ++c) a += qs[c*Tt + t] * ks[c*Tt + u];
            val = tanhf(a * (1.f/32.f)) * alpha;
        }
        attb[(size_t)n*65536 + (size_t)u*512 + h*128 + t] = f2bf(val);
    }
}

extern "C" void kernel_launch(void* const* d_in, const int* in_sizes, int n_in,
                              void* d_out, int out_size, void* d_ws, size_t ws_size,
                              hipStream_t stream) {
    const float* x       = (const float*)d_in[0];
    const float* w_in_s  = (const float*)d_in[1];
    const float* b_in_s  = (const float*)d_in[2];
    const float* att0s   = (const float*)d_in[3];
    const float* alphas  = (const float*)d_in[4];
    const float* w_out_s = (const float*)d_in[5];
    const float* b_out_s = (const float*)d_in[6];
    const float* g_out_s = (const float*)d_in[7];
    const float* be_out_s= (const float*)d_in[8];
    const float* w_ff_s  = (const float*)d_in[9];
    const float* b_ff_s  = (const float*)d_in[10];
    const float* g_ff_s  = (const float*)d_in[11];
    const float* be_ff_s = (const float*)d_in[12];
    const float* w_in_t  = (const float*)d_in[13];
    const float* b_in_t  = (const float*)d_in[14];
    const float* alphat_f= (const float*)d_in[15];
    const float* alphat_b= (const float*)d_in[16];
    const float* w_out_t = (const float*)d_in[17];
    const float* b_out_t = (const float*)d_in[18];
    const float* g_out_t = (const float*)d_in[19];
    const float* be_out_t= (const float*)d_in[20];
    const float* w_ff_t  = (const float*)d_in[21];
    const float* b_ff_t  = (const float*)d_in[22];
    const float* g_ff_t  = (const float*)d_in[23];
    const float* be_ff_t = (const float*)d_in[24];
    const float* w_tcn   = (const float*)d_in[25];
    const float* b_tcn   = (const float*)d_in[26];
    const float* g_tcn   = (const float*)d_in[27];
    const float* be_tcn  = (const float*)d_in[28];

    float* ws = (float*)d_ws;
    unsigned short* WB    = (unsigned short*)ws;
    unsigned short* QKBF  = (unsigned short*)(ws + 200000);
    unsigned short* S1BF  = (unsigned short*)(ws + 200000);   // S1T [col][128]
    unsigned short* ATSB  = (unsigned short*)(ws + 10030400);
    unsigned short* Y2BF  = (unsigned short*)(ws + 13870400); // Y2T [col][384]
    unsigned short* TOUTBP= (unsigned short*)(ws + 23710000); // padded base
    unsigned short* TOUTB = TOUTBP + 9600;                    // e=0 of n=0
    float*          SOUT  = ws + 33531200;
    unsigned short* ATTB  = (unsigned short*)(ws + 200000);
    unsigned short* XBARB = (unsigned short*)(ws + 1300000);  // [t][c]
    float*          QKT   = ws + 1600000;
    unsigned short* TMPB  = (unsigned short*)(ws + 2700000);  // row-major
    unsigned short* T1BF  = (unsigned short*)(ws + 46638400); // row-major
    float*          TOUT  = ws + 2700000;
    float* out = (float*)d_out;

    unsigned short* wbis = WB;
    unsigned short* wbos = WB + 24576;
    unsigned short* wbfs = WB + 73728;
    unsigned short* wbit = WB + 90112;
    unsigned short* wbot = WB + 122880;
    unsigned short* wbft = WB + 188416;
    unsigned short* wbtc = WB + 204800;

    dim3 blk(256);
    const float* NUL = nullptr;

    k_prep<<<1248, blk, 0, stream>>>(w_in_s, w_out_s, w_ff_s, w_in_t,
                                     w_out_t, w_ff_t, w_tcn, WB);

    // ---- spatial ----
    // qk_bf = W_in_s @ x + b  (BMODE4, D row-major) : 3200 blocks
    gemm_k<4,0,1><<<3200, blk, 0, stream>>>(
        wbis, x, nullptr, QKBF, NUL, b_in_s, NUL, NUL,
        192, 128, 128, 3200, 3200, 0L, 409600L, 614400L, 614400L, 50, 100);
    k_att_s<<<Nn*3*Tt, blk, 0, stream>>>(QKBF, att0s, alphas, ATSB);
    k_eins_mfma<<<dim3(Nn*32), blk, 0, stream>>>(x, ATSB, Y2BF);
    // s1T = lrelu(x + bn(W_out_s @ y2T + b))  (BMODE6 vec, DMODE1 flush)
    gemm_k<6,1,1><<<1600, blk, 0, stream>>>(
        wbos, Y2BF, nullptr, S1BF, x, b_out_s, g_out_s, be_out_s,
        128, 384, 384, 384, 3200, 0L, 1228800L, 409600L, 409600L, 50, 50);
    // sout = lrelu(x + bn(W_ff_s @ s1T + b))  (BMODE6 vec, D fp32 row-major)
    gemm_k<6,0,0><<<1600, blk, 0, stream>>>(
        wbfs, S1BF, SOUT, nullptr, x, b_ff_s, g_ff_s, be_ff_s,
        128, 128, 128, 128, 3200, 0L, 409600L, 409600L, 409600L, 50, 50);

    // ---- temporal ----
    k_mean<<<2048, blk, 0, stream>>>(SOUT, XBARB);
    // qkt = W_in_t @ xbarT + b  (BMODE6 vec) : 128 blocks
    gemm_k<6,0,0><<<128, blk, 0, stream>>>(
        wbit, XBARB, QKT, nullptr, NUL, b_in_t, NUL, NUL,
        256, 128, 128, 128, 128, 0L, 16384L, 32768L, 32768L, 2, 4);
    k_att_t<<<Nn*4, blk, 0, stream>>>(QKT, alphat_f, alphat_b, ATTB);
    // tmp_bf row-major = W_out_t_perm @ sout  (BMODE4, DMODE0) : 6400 blocks
    gemm_k<4,0,1><<<6400, blk, 0, stream>>>(
        wbot, SOUT, nullptr, TMPB, NUL, NUL, NUL, NUL,
        512, 128, 128, 3200, 3200, 0L, 409600L, 1638400L, 1638400L, 50, 200);
    // t1_bf row-major = lrelu(sout + bn(att @ tmp + b))  (BMODE3, DMODE2)
    gemm_k<3,2,1><<<1600, blk, 0, stream>>>(
        ATTB, TMPB, nullptr, T1BF, SOUT, b_out_t, g_out_t, be_out_t,
        128, 512, 512, 3200, 3200, 65536L, 1638400L, 409600L, 409600L, 50, 50);
    // TMPB dead -> zero TCN pad margins (TOUTBP overlaps TMPB/Y2T ranges)
    k_zpad<<<300, blk, 0, stream>>>(TOUTBP);
    // tout fp32 + TOUTB_T = lrelu(sout + bn(W_ff_t @ t1 + b)) (DMODE1 OM2)
    gemm_k<0,1,2><<<1600, blk, 0, stream>>>(
        wbft, T1BF, TOUT, TOUTB, SOUT, b_ff_t, g_ff_t, be_ff_t,
        128, 128, 128, 3200, 3200, 0L, 409600L, 409600L, 428800L, 50, 50);

    // ---- TCN ----
    // out = lrelu(tout + bn(conv7 @ toutbT + b))  (BMODE7 vec, padded)
    gemm_k<7,0,0><<<1600, blk, 0, stream>>>(
        wbtc, TOUTB, out, nullptr, TOUT, b_tcn, g_tcn, be_tcn,
        128, 896, 896, 0, 3200, 0L, 428800L, 409600L, 409600L, 50, 50);
}